// Round 1
// baseline (945.639 us; speedup 1.0000x reference)
//
#include <hip/hip_runtime.h>
#include <math.h>

#define LEN   5440
#define NB    2
#define MROWS (NB * LEN)   // 10880
#define DM    256
#define NH    8
#define HD    32
#define NLV   4
#define NPT   4
#define DFFN  1024

// ---------------------------------------------------------------------------
// Tiled fp32 GEMM: C[M,N] = (A (+ A2)) @ W + bias, optional ReLU.
// Requires M%64==0, N%64==0, K%16==0 (true for all shapes here).
// Block = 256 threads, tile 64x64, BK=16, 4x4 micro-tile per thread.
// ---------------------------------------------------------------------------
template <int RELU>
__global__ __launch_bounds__(256) void gemm_kernel(
    const float* __restrict__ A, const float* __restrict__ A2,
    const float* __restrict__ W, const float* __restrict__ bias,
    float* __restrict__ C, int M, int N, int K)
{
    __shared__ float As[16][65];                 // As[k][m]
    __shared__ __align__(16) float Bs[16][68];   // Bs[k][n]

    const int t  = threadIdx.x;
    const int m0 = blockIdx.y * 64;
    const int n0 = blockIdx.x * 64;
    const int tx = t & 15;        // 16 col-groups
    const int ty = t >> 4;        // 16 row-groups

    // A-tile load mapping: element i = t*4 .. t*4+3 ; m = i/16, k = i%16
    const int am = t >> 2;
    const int ak = (t & 3) * 4;
    // B-tile load mapping: k = i/64, n = i%64
    const int bk = t >> 4;
    const int bn = (t & 15) * 4;

    float acc[4][4] = {};

    for (int k0 = 0; k0 < K; k0 += 16) {
        float4 av = *(const float4*)(A + (long)(m0 + am) * K + k0 + ak);
        if (A2) {
            float4 a2 = *(const float4*)(A2 + (long)(m0 + am) * K + k0 + ak);
            av.x += a2.x; av.y += a2.y; av.z += a2.z; av.w += a2.w;
        }
        As[ak + 0][am] = av.x;
        As[ak + 1][am] = av.y;
        As[ak + 2][am] = av.z;
        As[ak + 3][am] = av.w;

        float4 bvv = *(const float4*)(W + (long)(k0 + bk) * N + n0 + bn);
        *(float4*)(&Bs[bk][bn]) = bvv;

        __syncthreads();
        #pragma unroll
        for (int kk = 0; kk < 16; ++kk) {
            float a[4], b[4];
            #pragma unroll
            for (int i = 0; i < 4; ++i) a[i] = As[kk][ty * 4 + i];
            #pragma unroll
            for (int j = 0; j < 4; ++j) b[j] = Bs[kk][tx * 4 + j];
            #pragma unroll
            for (int i = 0; i < 4; ++i)
                #pragma unroll
                for (int j = 0; j < 4; ++j)
                    acc[i][j] = fmaf(a[i], b[j], acc[i][j]);
        }
        __syncthreads();
    }

    float b0 = bias[n0 + tx * 4 + 0];
    float b1 = bias[n0 + tx * 4 + 1];
    float b2 = bias[n0 + tx * 4 + 2];
    float b3 = bias[n0 + tx * 4 + 3];
    #pragma unroll
    for (int i = 0; i < 4; ++i) {
        int row = m0 + ty * 4 + i;
        float4 o;
        o.x = acc[i][0] + b0;
        o.y = acc[i][1] + b1;
        o.z = acc[i][2] + b2;
        o.w = acc[i][3] + b3;
        if (RELU) {
            o.x = fmaxf(o.x, 0.f); o.y = fmaxf(o.y, 0.f);
            o.z = fmaxf(o.z, 0.f); o.w = fmaxf(o.w, 0.f);
        }
        *(float4*)(C + (long)row * N + n0 + tx * 4) = o;
    }
}

// ---------------------------------------------------------------------------
// Deformable attention sampling. One block per (n, q); 256 threads = 8 heads
// x 32 dims (d = tid&31 -> coalesced value gathers). Softmax over the 16
// (level,point) attention logits is done in registers (redundant per d-lane,
// L1-broadcast). Output layout: ATT[row*256 + h*32 + d] (head-major, matches
// reference transpose+reshape).
// ---------------------------------------------------------------------------
__global__ __launch_bounds__(256) void deform_attn_kernel(
    const float* __restrict__ V,    // (NB, LEN, NH, HD)
    const float* __restrict__ OFF,  // (MROWS, 256) = (h,lvl,p,2)
    const float* __restrict__ AW,   // (MROWS, 128) = (h,lvl*4+p) raw logits
    const float* __restrict__ vr,   // (NB, NLV, 2)
    float* __restrict__ ATT)        // (MROWS, 256)
{
    const int starts[5] = {0, 4096, 5120, 5376, 5440};
    const int dims[4]   = {64, 32, 16, 8};   // H == W per level

    const int blk = blockIdx.x;
    const int q   = blk % LEN;
    const int n   = blk / LEN;
    const int tid = threadIdx.x;
    const int d   = tid & 31;
    const int h   = tid >> 5;

    // level of this query + its grid position -> reference point
    int lq = 3;
    if (q < 4096) lq = 0; else if (q < 5120) lq = 1; else if (q < 5376) lq = 2;
    const int r  = q - starts[lq];
    const int Wq = dims[lq];
    const int gy = r / Wq, gx = r % Wq;
    const float vrxq = vr[(n * NLV + lq) * 2 + 0];
    const float vryq = vr[(n * NLV + lq) * 2 + 1];
    const float rx = (gx + 0.5f) / (vrxq * Wq);
    const float ry = (gy + 0.5f) / (vryq * Wq);

    const long row = (long)n * LEN + q;

    // softmax over 16 logits of this head
    const float* awp = AW + row * (NH * NLV * NPT) + h * (NLV * NPT);
    float a[16];
    float mx = -1e30f;
    #pragma unroll
    for (int i = 0; i < 16; ++i) { a[i] = awp[i]; mx = fmaxf(mx, a[i]); }
    float s = 0.f;
    #pragma unroll
    for (int i = 0; i < 16; ++i) { a[i] = __expf(a[i] - mx); s += a[i]; }
    const float inv = 1.f / s;

    const float* offp = OFF + row * 256 + h * 32;   // (lvl,p,2)

    float acc = 0.f;
    #pragma unroll
    for (int lvl = 0; lvl < NLV; ++lvl) {
        const int Hl = dims[lvl];
        const int Wl = Hl;
        const int sb = starts[lvl];
        const float lx = rx * vr[(n * NLV + lvl) * 2 + 0];
        const float ly = ry * vr[(n * NLV + lvl) * 2 + 1];
        const float* vbase = V + (((long)n * LEN + sb) * NH + h) * HD + d;
        #pragma unroll
        for (int p = 0; p < NPT; ++p) {
            const float ox = offp[lvl * 8 + p * 2 + 0];
            const float oy = offp[lvl * 8 + p * 2 + 1];
            const float x = (lx + ox / Wl) * Wl - 0.5f;
            const float y = (ly + oy / Hl) * Hl - 0.5f;
            const float x0f = floorf(x), y0f = floorf(y);
            const int ix0 = (int)x0f, iy0 = (int)y0f;
            const float wx1 = x - x0f, wy1 = y - y0f;
            const float wx0 = 1.f - wx1, wy0 = 1.f - wy1;
            const float awv = a[lvl * 4 + p] * inv;

            float sv = 0.f;
            // corner (ix0, iy0)
            if (ix0 >= 0 && ix0 < Wl && iy0 >= 0 && iy0 < Hl)
                sv += wx0 * wy0 * vbase[(long)(iy0 * Wl + ix0) * (NH * HD)];
            // corner (ix0+1, iy0)
            if (ix0 + 1 >= 0 && ix0 + 1 < Wl && iy0 >= 0 && iy0 < Hl)
                sv += wx1 * wy0 * vbase[(long)(iy0 * Wl + ix0 + 1) * (NH * HD)];
            // corner (ix0, iy0+1)
            if (ix0 >= 0 && ix0 < Wl && iy0 + 1 >= 0 && iy0 + 1 < Hl)
                sv += wx0 * wy1 * vbase[(long)((iy0 + 1) * Wl + ix0) * (NH * HD)];
            // corner (ix0+1, iy0+1)
            if (ix0 + 1 >= 0 && ix0 + 1 < Wl && iy0 + 1 >= 0 && iy0 + 1 < Hl)
                sv += wx1 * wy1 * vbase[(long)((iy0 + 1) * Wl + ix0 + 1) * (NH * HD)];

            acc += awv * sv;
        }
    }
    ATT[row * DM + h * HD + d] = acc;
}

// ---------------------------------------------------------------------------
// out = LayerNorm(X + Y) * g + b ; one block (256 threads) per row.
// ---------------------------------------------------------------------------
__global__ __launch_bounds__(256) void add_ln_kernel(
    const float* __restrict__ X, const float* __restrict__ Y,
    const float* __restrict__ g, const float* __restrict__ b,
    float* __restrict__ OUT)
{
    const long row = blockIdx.x;
    const int  t   = threadIdx.x;
    const int lane = t & 63, wid = t >> 6;
    __shared__ float red[4];

    float v = X[row * DM + t] + Y[row * DM + t];

    float s = v;
    #pragma unroll
    for (int o = 32; o > 0; o >>= 1) s += __shfl_down(s, o, 64);
    if (lane == 0) red[wid] = s;
    __syncthreads();
    const float mean = (red[0] + red[1] + red[2] + red[3]) * (1.f / DM);
    __syncthreads();

    const float dv = v - mean;
    float s2 = dv * dv;
    #pragma unroll
    for (int o = 32; o > 0; o >>= 1) s2 += __shfl_down(s2, o, 64);
    if (lane == 0) red[wid] = s2;
    __syncthreads();
    const float var = (red[0] + red[1] + red[2] + red[3]) * (1.f / DM);

    OUT[row * DM + t] = dv * rsqrtf(var + 1e-5f) * g[t] + b[t];
}

// ---------------------------------------------------------------------------
extern "C" void kernel_launch(void* const* d_in, const int* in_sizes, int n_in,
                              void* d_out, int out_size, void* d_ws, size_t ws_size,
                              hipStream_t stream)
{
    const float* src = (const float*)d_in[0];
    const float* pos = (const float*)d_in[1];
    const float* vr  = (const float*)d_in[2];
    const float* Wv_   = (const float*)d_in[3];
    const float* bv_   = (const float*)d_in[4];
    const float* Woff_ = (const float*)d_in[5];
    const float* boff_ = (const float*)d_in[6];
    const float* Wa_   = (const float*)d_in[7];
    const float* ba_   = (const float*)d_in[8];
    const float* Wo_   = (const float*)d_in[9];
    const float* bo_   = (const float*)d_in[10];
    const float* g1_   = (const float*)d_in[11];
    const float* be1_  = (const float*)d_in[12];
    const float* Wl1_  = (const float*)d_in[13];
    const float* bl1_  = (const float*)d_in[14];
    const float* Wl2_  = (const float*)d_in[15];
    const float* bl2_  = (const float*)d_in[16];
    const float* g2_   = (const float*)d_in[17];
    const float* be2_  = (const float*)d_in[18];

    float* ws = (float*)d_ws;
    const long SZ = (long)MROWS * DM;       // 2,785,280
    float* V   = ws;                         // (MROWS, 256)
    float* OFF = V   + SZ;                   // (MROWS, 256)
    float* AW  = OFF + SZ;                   // (MROWS, 128)
    float* ATT = AW  + (long)MROWS * 128;    // (MROWS, 256)
    float* AO  = ATT + SZ;                   // (MROWS, 256)
    float* FFN = AO  + SZ;                   // (MROWS, 1024)
    float* XA  = FFN + (long)MROWS * DFFN;   // (MROWS, 256)
    float* XB  = XA  + SZ;                   // (MROWS, 256)

    const dim3 blk(256);
    const dim3 g256(DM / 64, MROWS / 64);    // (4, 170)
    const dim3 g128(128 / 64, MROWS / 64);   // (2, 170)
    const dim3 g1024(DFFN / 64, MROWS / 64); // (16, 170)

    const float* cur = src;
    for (int l = 0; l < 2; ++l) {
        const float* Wv   = Wv_   + (long)l * DM * DM;
        const float* bv   = bv_   + (long)l * DM;
        const float* Woff = Woff_ + (long)l * DM * 256;
        const float* boff = boff_ + (long)l * 256;
        const float* Wa   = Wa_   + (long)l * DM * 128;
        const float* ba   = ba_   + (long)l * 128;
        const float* Wo   = Wo_   + (long)l * DM * DM;
        const float* bo   = bo_   + (long)l * DM;
        const float* g1   = g1_   + (long)l * DM;
        const float* be1  = be1_  + (long)l * DM;
        const float* Wl1  = Wl1_  + (long)l * DM * DFFN;
        const float* bl1  = bl1_  + (long)l * DFFN;
        const float* Wl2  = Wl2_  + (long)l * DFFN * DM;
        const float* bl2  = bl2_  + (long)l * DM;
        const float* g2   = g2_   + (long)l * DM;
        const float* be2  = be2_  + (long)l * DM;

        // value = cur @ Wv + bv
        hipLaunchKernelGGL((gemm_kernel<0>), g256, blk, 0, stream,
                           cur, (const float*)nullptr, Wv, bv, V, MROWS, DM, DM);
        // off = (cur + pos) @ Woff + boff
        hipLaunchKernelGGL((gemm_kernel<0>), g256, blk, 0, stream,
                           cur, pos, Woff, boff, OFF, MROWS, 256, DM);
        // aw logits = (cur + pos) @ Wa + ba
        hipLaunchKernelGGL((gemm_kernel<0>), g128, blk, 0, stream,
                           cur, pos, Wa, ba, AW, MROWS, 128, DM);
        // sampling
        hipLaunchKernelGGL(deform_attn_kernel, dim3(MROWS), blk, 0, stream,
                           V, OFF, AW, vr, ATT);
        // attn = ATT @ Wo + bo
        hipLaunchKernelGGL((gemm_kernel<0>), g256, blk, 0, stream,
                           ATT, (const float*)nullptr, Wo, bo, AO, MROWS, DM, DM);
        // x = LN(cur + attn)
        hipLaunchKernelGGL(add_ln_kernel, dim3(MROWS), blk, 0, stream,
                           cur, AO, g1, be1, XA);
        // ffn hidden = relu(x @ Wl1 + bl1)
        hipLaunchKernelGGL((gemm_kernel<1>), g1024, blk, 0, stream,
                           XA, (const float*)nullptr, Wl1, bl1, FFN, MROWS, DFFN, DM);
        // ffn out = hidden @ Wl2 + bl2
        hipLaunchKernelGGL((gemm_kernel<0>), g256, blk, 0, stream,
                           FFN, (const float*)nullptr, Wl2, bl2, AO, MROWS, DM, DFFN);
        // out = LN(x + ffn)
        float* dst = (l == 1) ? (float*)d_out : XB;
        hipLaunchKernelGGL(add_ln_kernel, dim3(MROWS), blk, 0, stream,
                           XA, AO, g2, be2, dst);
        cur = dst;
    }
}

// Round 2
// 583.219 us; speedup vs baseline: 1.6214x; 1.6214x over previous
//
#include <hip/hip_runtime.h>
#include <math.h>

#define LEN   5440
#define NB    2
#define MROWS (NB * LEN)   // 10880
#define DM    256
#define NH    8
#define HD    32
#define NLV   4
#define NPT   4
#define DFFN  1024

typedef __attribute__((ext_vector_type(8))) short bf16x8;
typedef __attribute__((ext_vector_type(4))) float f32x4;

__device__ __forceinline__ short f2bf(float f) {
    union { float f; unsigned u; } cv; cv.f = f;
    unsigned r = cv.u + 0x7fffu + ((cv.u >> 16) & 1u);   // RNE
    return (short)(r >> 16);
}

// ---------------------------------------------------------------------------
// One-shot: transpose+convert all 12 weight matrices fp32 [K][N] -> bf16 [N][K].
// Per-layer dst layout (shorts): Wv@0, Woff@65536, Wa@131072, Wo@163840,
// Wl1@229376, Wl2@491520 ; layer stride 753664.
// grid = 1472 tiles of 32x32 (736 per layer).
// ---------------------------------------------------------------------------
__global__ __launch_bounds__(256) void transpose_convert_all(
    const float* __restrict__ Wv,  const float* __restrict__ Woff,
    const float* __restrict__ Wa,  const float* __restrict__ Wo,
    const float* __restrict__ Wl1, const float* __restrict__ Wl2,
    short* __restrict__ out)
{
    int bx = blockIdx.x;
    int l  = bx / 736;
    int t  = bx % 736;
    const float* src; int K, N; long doff;
    if      (t < 64)  { src = Wv;   K = 256;  N = 256;  doff = 0;      }
    else if (t < 128) { src = Woff; K = 256;  N = 256;  doff = 65536;  t -= 64;  }
    else if (t < 160) { src = Wa;   K = 256;  N = 128;  doff = 131072; t -= 128; }
    else if (t < 224) { src = Wo;   K = 256;  N = 256;  doff = 163840; t -= 160; }
    else if (t < 480) { src = Wl1;  K = 256;  N = 1024; doff = 229376; t -= 224; }
    else              { src = Wl2;  K = 1024; N = 256;  doff = 491520; t -= 480; }
    src += (long)l * K * N;
    short* dst = out + (long)l * 753664 + doff;

    const int ntx = N / 32;
    const int n0 = (t % ntx) * 32, k0 = (t / ntx) * 32;

    __shared__ short T[32][33];
    const int tid = threadIdx.x;
    {
        const int n = tid & 31, kq = tid >> 5;       // kq 0..7
        #pragma unroll
        for (int i = 0; i < 4; ++i) {
            int k = kq * 4 + i;
            T[n][k] = f2bf(src[(long)(k0 + k) * N + n0 + n]);
        }
    }
    __syncthreads();
    {
        const int k = tid & 31, nq = tid >> 5;
        #pragma unroll
        for (int i = 0; i < 4; ++i) {
            int n = nq * 4 + i;
            dst[(long)(n0 + n) * K + k0 + k] = T[n][k];
        }
    }
}

// ---------------------------------------------------------------------------
// MFMA bf16 GEMM: C[M,N] = (A (+A2)) @ W + bias, optional ReLU.
// A fp32 [M][K] (converted to bf16 in staging), Wt bf16 [N][K] (pre-transposed).
// Block 256 thr = 4 waves; tile 64x64; each wave owns a 32x32 quadrant as
// 2x2 subtiles of v_mfma_f32_16x16x32_bf16. BK=32. fp32 accumulate.
// Frag layouts (measured, m89/m91): A[m=lane&15][k=(lane>>4)*8+j],
// B[n=lane&15][k=(lane>>4)*8+j], D col=lane&15,row=(lane>>4)*4+reg.
// ---------------------------------------------------------------------------
template <int RELU>
__global__ __launch_bounds__(256) void gemm_mfma(
    const float* __restrict__ A, const float* __restrict__ A2,
    const short* __restrict__ Wt, const float* __restrict__ bias,
    float* __restrict__ C, int M, int N, int K)
{
    __shared__ __align__(16) short As[64 * 40];   // row stride 40 shorts (80 B)
    __shared__ __align__(16) short Bs[64 * 40];

    const int t    = threadIdx.x;
    const int m0   = blockIdx.y * 64;
    const int n0   = blockIdx.x * 64;
    const int wave = t >> 6, lane = t & 63;
    const int wm   = (wave & 1) * 32;
    const int wn   = (wave >> 1) * 32;
    const int sr   = t >> 2;          // staging row 0..63
    const int sk   = (t & 3) * 8;     // staging k offset {0,8,16,24}
    const int lm   = lane & 15;
    const int lk   = (lane >> 4) * 8;

    f32x4 acc[2][2] = {};

    for (int k0 = 0; k0 < K; k0 += 32) {
        // ---- stage A (fp32 -> bf16) ----
        const float* ap = A + (long)(m0 + sr) * K + k0 + sk;
        float4 a0 = *(const float4*)(ap);
        float4 a1 = *(const float4*)(ap + 4);
        if (A2) {
            const float* a2p = A2 + (long)(m0 + sr) * K + k0 + sk;
            float4 c0 = *(const float4*)(a2p);
            float4 c1 = *(const float4*)(a2p + 4);
            a0.x += c0.x; a0.y += c0.y; a0.z += c0.z; a0.w += c0.w;
            a1.x += c1.x; a1.y += c1.y; a1.z += c1.z; a1.w += c1.w;
        }
        bf16x8 av;
        av[0] = f2bf(a0.x); av[1] = f2bf(a0.y); av[2] = f2bf(a0.z); av[3] = f2bf(a0.w);
        av[4] = f2bf(a1.x); av[5] = f2bf(a1.y); av[6] = f2bf(a1.z); av[7] = f2bf(a1.w);
        *(bf16x8*)(&As[sr * 40 + sk]) = av;

        // ---- stage B (already bf16, [N][K]) ----
        bf16x8 bv = *(const bf16x8*)(Wt + (long)(n0 + sr) * K + k0 + sk);
        *(bf16x8*)(&Bs[sr * 40 + sk]) = bv;

        __syncthreads();

        bf16x8 af0 = *(const bf16x8*)(&As[(wm + lm)      * 40 + lk]);
        bf16x8 af1 = *(const bf16x8*)(&As[(wm + 16 + lm) * 40 + lk]);
        bf16x8 bf0 = *(const bf16x8*)(&Bs[(wn + lm)      * 40 + lk]);
        bf16x8 bf1 = *(const bf16x8*)(&Bs[(wn + 16 + lm) * 40 + lk]);

        acc[0][0] = __builtin_amdgcn_mfma_f32_16x16x32_bf16(af0, bf0, acc[0][0], 0, 0, 0);
        acc[0][1] = __builtin_amdgcn_mfma_f32_16x16x32_bf16(af0, bf1, acc[0][1], 0, 0, 0);
        acc[1][0] = __builtin_amdgcn_mfma_f32_16x16x32_bf16(af1, bf0, acc[1][0], 0, 0, 0);
        acc[1][1] = __builtin_amdgcn_mfma_f32_16x16x32_bf16(af1, bf1, acc[1][1], 0, 0, 0);

        __syncthreads();
    }

    // ---- epilogue ----
    const int col = lane & 15;
    const int rq  = (lane >> 4) * 4;
    #pragma unroll
    for (int mi = 0; mi < 2; ++mi) {
        #pragma unroll
        for (int nj = 0; nj < 2; ++nj) {
            const int gn = n0 + wn + nj * 16 + col;
            const float bb = bias[gn];
            #pragma unroll
            for (int r = 0; r < 4; ++r) {
                const int gm = m0 + wm + mi * 16 + rq + r;
                float v = acc[mi][nj][r] + bb;
                if (RELU) v = fmaxf(v, 0.f);
                C[(long)gm * N + gn] = v;
            }
        }
    }
}

// ---------------------------------------------------------------------------
// Deformable attention sampling (unchanged from R1).
// ---------------------------------------------------------------------------
__global__ __launch_bounds__(256) void deform_attn_kernel(
    const float* __restrict__ V,    // (NB, LEN, NH, HD)
    const float* __restrict__ OFF,  // (MROWS, 256)
    const float* __restrict__ AW,   // (MROWS, 128)
    const float* __restrict__ vr,   // (NB, NLV, 2)
    float* __restrict__ ATT)        // (MROWS, 256)
{
    const int starts[5] = {0, 4096, 5120, 5376, 5440};
    const int dims[4]   = {64, 32, 16, 8};

    const int blk = blockIdx.x;
    const int q   = blk % LEN;
    const int n   = blk / LEN;
    const int tid = threadIdx.x;
    const int d   = tid & 31;
    const int h   = tid >> 5;

    int lq = 3;
    if (q < 4096) lq = 0; else if (q < 5120) lq = 1; else if (q < 5376) lq = 2;
    const int r  = q - starts[lq];
    const int Wq = dims[lq];
    const int gy = r / Wq, gx = r % Wq;
    const float vrxq = vr[(n * NLV + lq) * 2 + 0];
    const float vryq = vr[(n * NLV + lq) * 2 + 1];
    const float rx = (gx + 0.5f) / (vrxq * Wq);
    const float ry = (gy + 0.5f) / (vryq * Wq);

    const long row = (long)n * LEN + q;

    const float* awp = AW + row * (NH * NLV * NPT) + h * (NLV * NPT);
    float a[16];
    float mx = -1e30f;
    #pragma unroll
    for (int i = 0; i < 16; ++i) { a[i] = awp[i]; mx = fmaxf(mx, a[i]); }
    float s = 0.f;
    #pragma unroll
    for (int i = 0; i < 16; ++i) { a[i] = __expf(a[i] - mx); s += a[i]; }
    const float inv = 1.f / s;

    const float* offp = OFF + row * 256 + h * 32;

    float acc = 0.f;
    #pragma unroll
    for (int lvl = 0; lvl < NLV; ++lvl) {
        const int Hl = dims[lvl];
        const int Wl = Hl;
        const int sb = starts[lvl];
        const float lx = rx * vr[(n * NLV + lvl) * 2 + 0];
        const float ly = ry * vr[(n * NLV + lvl) * 2 + 1];
        const float* vbase = V + (((long)n * LEN + sb) * NH + h) * HD + d;
        #pragma unroll
        for (int p = 0; p < NPT; ++p) {
            const float ox = offp[lvl * 8 + p * 2 + 0];
            const float oy = offp[lvl * 8 + p * 2 + 1];
            const float x = (lx + ox / Wl) * Wl - 0.5f;
            const float y = (ly + oy / Hl) * Hl - 0.5f;
            const float x0f = floorf(x), y0f = floorf(y);
            const int ix0 = (int)x0f, iy0 = (int)y0f;
            const float wx1 = x - x0f, wy1 = y - y0f;
            const float wx0 = 1.f - wx1, wy0 = 1.f - wy1;
            const float awv = a[lvl * 4 + p] * inv;

            float sv = 0.f;
            if (ix0 >= 0 && ix0 < Wl && iy0 >= 0 && iy0 < Hl)
                sv += wx0 * wy0 * vbase[(long)(iy0 * Wl + ix0) * (NH * HD)];
            if (ix0 + 1 >= 0 && ix0 + 1 < Wl && iy0 >= 0 && iy0 < Hl)
                sv += wx1 * wy0 * vbase[(long)(iy0 * Wl + ix0 + 1) * (NH * HD)];
            if (ix0 >= 0 && ix0 < Wl && iy0 + 1 >= 0 && iy0 + 1 < Hl)
                sv += wx0 * wy1 * vbase[(long)((iy0 + 1) * Wl + ix0) * (NH * HD)];
            if (ix0 + 1 >= 0 && ix0 + 1 < Wl && iy0 + 1 >= 0 && iy0 + 1 < Hl)
                sv += wx1 * wy1 * vbase[(long)((iy0 + 1) * Wl + ix0 + 1) * (NH * HD)];

            acc += awv * sv;
        }
    }
    ATT[row * DM + h * HD + d] = acc;
}

// ---------------------------------------------------------------------------
// out = LayerNorm(X + Y) * g + b ; one block (256 threads) per row.
// ---------------------------------------------------------------------------
__global__ __launch_bounds__(256) void add_ln_kernel(
    const float* __restrict__ X, const float* __restrict__ Y,
    const float* __restrict__ g, const float* __restrict__ b,
    float* __restrict__ OUT)
{
    const long row = blockIdx.x;
    const int  t   = threadIdx.x;
    const int lane = t & 63, wid = t >> 6;
    __shared__ float red[4];

    float v = X[row * DM + t] + Y[row * DM + t];

    float s = v;
    #pragma unroll
    for (int o = 32; o > 0; o >>= 1) s += __shfl_down(s, o, 64);
    if (lane == 0) red[wid] = s;
    __syncthreads();
    const float mean = (red[0] + red[1] + red[2] + red[3]) * (1.f / DM);
    __syncthreads();

    const float dv = v - mean;
    float s2 = dv * dv;
    #pragma unroll
    for (int o = 32; o > 0; o >>= 1) s2 += __shfl_down(s2, o, 64);
    if (lane == 0) red[wid] = s2;
    __syncthreads();
    const float var = (red[0] + red[1] + red[2] + red[3]) * (1.f / DM);

    OUT[row * DM + t] = dv * rsqrtf(var + 1e-5f) * g[t] + b[t];
}

// ---------------------------------------------------------------------------
extern "C" void kernel_launch(void* const* d_in, const int* in_sizes, int n_in,
                              void* d_out, int out_size, void* d_ws, size_t ws_size,
                              hipStream_t stream)
{
    const float* src = (const float*)d_in[0];
    const float* pos = (const float*)d_in[1];
    const float* vr  = (const float*)d_in[2];
    const float* Wv_   = (const float*)d_in[3];
    const float* bv_   = (const float*)d_in[4];
    const float* Woff_ = (const float*)d_in[5];
    const float* boff_ = (const float*)d_in[6];
    const float* Wa_   = (const float*)d_in[7];
    const float* ba_   = (const float*)d_in[8];
    const float* Wo_   = (const float*)d_in[9];
    const float* bo_   = (const float*)d_in[10];
    const float* g1_   = (const float*)d_in[11];
    const float* be1_  = (const float*)d_in[12];
    const float* Wl1_  = (const float*)d_in[13];
    const float* bl1_  = (const float*)d_in[14];
    const float* Wl2_  = (const float*)d_in[15];
    const float* bl2_  = (const float*)d_in[16];
    const float* g2_   = (const float*)d_in[17];
    const float* be2_  = (const float*)d_in[18];

    float* ws = (float*)d_ws;
    const long SZ = (long)MROWS * DM;        // 2,785,280
    float* V   = ws;                          // (MROWS, 256)
    float* OFF = V   + SZ;                    // (MROWS, 256)
    float* AW  = OFF + SZ;                    // (MROWS, 128)
    float* ATT = AW  + (long)MROWS * 128;     // (MROWS, 256)
    float* AO  = ATT + SZ;                    // (MROWS, 256)
    float* FFN = AO  + SZ;                    // (MROWS, 1024)
    float* XA  = FFN + (long)MROWS * DFFN;    // (MROWS, 256)
    float* XB  = XA  + SZ;                    // (MROWS, 256)
    short* Wt  = (short*)(XB + SZ);           // 2 x 753664 bf16 weights

    const dim3 blk(256);
    const dim3 g256(DM / 64, MROWS / 64);     // (4, 170)
    const dim3 g128(128 / 64, MROWS / 64);    // (2, 170)
    const dim3 g1024(DFFN / 64, MROWS / 64);  // (16, 170)

    // transpose+convert all weights once (covers both layers)
    hipLaunchKernelGGL(transpose_convert_all, dim3(1472), blk, 0, stream,
                       Wv_, Woff_, Wa_, Wo_, Wl1_, Wl2_, Wt);

    const float* cur = src;
    for (int l = 0; l < 2; ++l) {
        const short* Wv   = Wt + (long)l * 753664 + 0;
        const short* Woff = Wt + (long)l * 753664 + 65536;
        const short* Wa   = Wt + (long)l * 753664 + 131072;
        const short* Wo   = Wt + (long)l * 753664 + 163840;
        const short* Wl1  = Wt + (long)l * 753664 + 229376;
        const short* Wl2  = Wt + (long)l * 753664 + 491520;
        const float* bv   = bv_   + (long)l * DM;
        const float* boff = boff_ + (long)l * 256;
        const float* ba   = ba_   + (long)l * 128;
        const float* bo   = bo_   + (long)l * DM;
        const float* g1   = g1_   + (long)l * DM;
        const float* be1  = be1_  + (long)l * DM;
        const float* bl1  = bl1_  + (long)l * DFFN;
        const float* bl2  = bl2_  + (long)l * DM;
        const float* g2   = g2_   + (long)l * DM;
        const float* be2  = be2_  + (long)l * DM;

        hipLaunchKernelGGL((gemm_mfma<0>), g256, blk, 0, stream,
                           cur, (const float*)nullptr, Wv, bv, V, MROWS, DM, DM);
        hipLaunchKernelGGL((gemm_mfma<0>), g256, blk, 0, stream,
                           cur, pos, Woff, boff, OFF, MROWS, 256, DM);
        hipLaunchKernelGGL((gemm_mfma<0>), g128, blk, 0, stream,
                           cur, pos, Wa, ba, AW, MROWS, 128, DM);
        hipLaunchKernelGGL(deform_attn_kernel, dim3(MROWS), blk, 0, stream,
                           V, OFF, AW, vr, ATT);
        hipLaunchKernelGGL((gemm_mfma<0>), g256, blk, 0, stream,
                           ATT, (const float*)nullptr, Wo, bo, AO, MROWS, DM, DM);
        hipLaunchKernelGGL(add_ln_kernel, dim3(MROWS), blk, 0, stream,
                           cur, AO, g1, be1, XA);
        hipLaunchKernelGGL((gemm_mfma<1>), g1024, blk, 0, stream,
                           XA, (const float*)nullptr, Wl1, bl1, FFN, MROWS, DFFN, DM);
        hipLaunchKernelGGL((gemm_mfma<0>), g256, blk, 0, stream,
                           FFN, (const float*)nullptr, Wl2, bl2, AO, MROWS, DM, DFFN);
        float* dst = (l == 1) ? (float*)d_out : XB;
        hipLaunchKernelGGL(add_ln_kernel, dim3(MROWS), blk, 0, stream,
                           XA, AO, g2, be2, dst);
        cur = dst;
    }
}

// Round 3
// 408.712 us; speedup vs baseline: 2.3137x; 1.4270x over previous
//
#include <hip/hip_runtime.h>
#include <math.h>

#define LEN   5440
#define NB    2
#define MROWS (NB * LEN)   // 10880
#define DM    256
#define NH    8
#define HD    32
#define NLV   4
#define NPT   4
#define DFFN  1024

typedef __attribute__((ext_vector_type(8))) short bf16x8;
typedef __attribute__((ext_vector_type(4))) float f32x4;

__device__ __forceinline__ short f2bf(float f) {
    union { float f; unsigned u; } cv; cv.f = f;
    unsigned r = cv.u + 0x7fffu + ((cv.u >> 16) & 1u);   // RNE
    return (short)(r >> 16);
}

// ---------------------------------------------------------------------------
// One-shot: transpose+convert all 12 weight matrices fp32 [K][N] -> bf16 [N][K].
// ---------------------------------------------------------------------------
__global__ __launch_bounds__(256) void transpose_convert_all(
    const float* __restrict__ Wv,  const float* __restrict__ Woff,
    const float* __restrict__ Wa,  const float* __restrict__ Wo,
    const float* __restrict__ Wl1, const float* __restrict__ Wl2,
    short* __restrict__ out)
{
    int bx = blockIdx.x;
    int l  = bx / 736;
    int t  = bx % 736;
    const float* src; int K, N; long doff;
    if      (t < 64)  { src = Wv;   K = 256;  N = 256;  doff = 0;      }
    else if (t < 128) { src = Woff; K = 256;  N = 256;  doff = 65536;  t -= 64;  }
    else if (t < 160) { src = Wa;   K = 256;  N = 128;  doff = 131072; t -= 128; }
    else if (t < 224) { src = Wo;   K = 256;  N = 256;  doff = 163840; t -= 160; }
    else if (t < 480) { src = Wl1;  K = 256;  N = 1024; doff = 229376; t -= 224; }
    else              { src = Wl2;  K = 1024; N = 256;  doff = 491520; t -= 480; }
    src += (long)l * K * N;
    short* dst = out + (long)l * 753664 + doff;

    const int ntx = N / 32;
    const int n0 = (t % ntx) * 32, k0 = (t / ntx) * 32;

    __shared__ short T[32][33];
    const int tid = threadIdx.x;
    {
        const int n = tid & 31, kq = tid >> 5;
        #pragma unroll
        for (int i = 0; i < 4; ++i) {
            int k = kq * 4 + i;
            T[n][k] = f2bf(src[(long)(k0 + k) * N + n0 + n]);
        }
    }
    __syncthreads();
    {
        const int k = tid & 31, nq = tid >> 5;
        #pragma unroll
        for (int i = 0; i < 4; ++i) {
            int n = nq * 4 + i;
            dst[(long)(n0 + n) * K + k0 + k] = T[n][k];
        }
    }
}

// ---------------------------------------------------------------------------
// MFMA bf16 GEMM (unchanged from R2): C = (A(+A2)) @ W + bias, opt ReLU.
// ---------------------------------------------------------------------------
template <int RELU>
__global__ __launch_bounds__(256) void gemm_mfma(
    const float* __restrict__ A, const float* __restrict__ A2,
    const short* __restrict__ Wt, const float* __restrict__ bias,
    float* __restrict__ C, int M, int N, int K)
{
    __shared__ __align__(16) short As[64 * 40];
    __shared__ __align__(16) short Bs[64 * 40];

    const int t    = threadIdx.x;
    const int m0   = blockIdx.y * 64;
    const int n0   = blockIdx.x * 64;
    const int wave = t >> 6, lane = t & 63;
    const int wm   = (wave & 1) * 32;
    const int wn   = (wave >> 1) * 32;
    const int sr   = t >> 2;
    const int sk   = (t & 3) * 8;
    const int lm   = lane & 15;
    const int lk   = (lane >> 4) * 8;

    f32x4 acc[2][2] = {};

    for (int k0 = 0; k0 < K; k0 += 32) {
        const float* ap = A + (long)(m0 + sr) * K + k0 + sk;
        float4 a0 = *(const float4*)(ap);
        float4 a1 = *(const float4*)(ap + 4);
        if (A2) {
            const float* a2p = A2 + (long)(m0 + sr) * K + k0 + sk;
            float4 c0 = *(const float4*)(a2p);
            float4 c1 = *(const float4*)(a2p + 4);
            a0.x += c0.x; a0.y += c0.y; a0.z += c0.z; a0.w += c0.w;
            a1.x += c1.x; a1.y += c1.y; a1.z += c1.z; a1.w += c1.w;
        }
        bf16x8 av;
        av[0] = f2bf(a0.x); av[1] = f2bf(a0.y); av[2] = f2bf(a0.z); av[3] = f2bf(a0.w);
        av[4] = f2bf(a1.x); av[5] = f2bf(a1.y); av[6] = f2bf(a1.z); av[7] = f2bf(a1.w);
        *(bf16x8*)(&As[sr * 40 + sk]) = av;

        bf16x8 bv = *(const bf16x8*)(Wt + (long)(n0 + sr) * K + k0 + sk);
        *(bf16x8*)(&Bs[sr * 40 + sk]) = bv;

        __syncthreads();

        bf16x8 af0 = *(const bf16x8*)(&As[(wm + lm)      * 40 + lk]);
        bf16x8 af1 = *(const bf16x8*)(&As[(wm + 16 + lm) * 40 + lk]);
        bf16x8 bf0 = *(const bf16x8*)(&Bs[(wn + lm)      * 40 + lk]);
        bf16x8 bf1 = *(const bf16x8*)(&Bs[(wn + 16 + lm) * 40 + lk]);

        acc[0][0] = __builtin_amdgcn_mfma_f32_16x16x32_bf16(af0, bf0, acc[0][0], 0, 0, 0);
        acc[0][1] = __builtin_amdgcn_mfma_f32_16x16x32_bf16(af0, bf1, acc[0][1], 0, 0, 0);
        acc[1][0] = __builtin_amdgcn_mfma_f32_16x16x32_bf16(af1, bf0, acc[1][0], 0, 0, 0);
        acc[1][1] = __builtin_amdgcn_mfma_f32_16x16x32_bf16(af1, bf1, acc[1][1], 0, 0, 0);

        __syncthreads();
    }

    const int col = lane & 15;
    const int rq  = (lane >> 4) * 4;
    #pragma unroll
    for (int mi = 0; mi < 2; ++mi) {
        #pragma unroll
        for (int nj = 0; nj < 2; ++nj) {
            const int gn = n0 + wn + nj * 16 + col;
            const float bb = bias[gn];
            #pragma unroll
            for (int r = 0; r < 4; ++r) {
                const int gm = m0 + wm + mi * 16 + rq + r;
                float v = acc[mi][nj][r] + bb;
                if (RELU) v = fmaxf(v, 0.f);
                C[(long)gm * N + gn] = v;
            }
        }
    }
}

// ---------------------------------------------------------------------------
// Deformable attention sampling v2. One WAVE per query (4 queries/block).
// lane = h*8 + d4 : lane owns dims [d4*4 .. d4*4+3] of head h -> float4
// gathers from V. Softmax + location math redundant only 8x (was 32x).
// Corner handling: clamp index, zero weight (no divergence; matches ref).
// ---------------------------------------------------------------------------
__global__ __launch_bounds__(256) void deform_attn_v2(
    const float4* __restrict__ V4,   // (NB, LEN, NH, 8) float4
    const float* __restrict__ OFF,   // (MROWS, 256)
    const float* __restrict__ AW,    // (MROWS, 128)
    const float* __restrict__ vr,    // (NB, NLV, 2)
    float4* __restrict__ ATT4)       // (MROWS, 64) float4
{
    const int starts[5] = {0, 4096, 5120, 5376, 5440};
    const int dims[4]   = {64, 32, 16, 8};

    const int wave = threadIdx.x >> 6;
    const int lane = threadIdx.x & 63;
    const int h    = lane >> 3;
    const int d4   = lane & 7;

    const int gq = blockIdx.x * 4 + wave;   // 0..MROWS-1
    const int n  = gq / LEN;
    const int q  = gq % LEN;

    int lq = 3;
    if (q < 4096) lq = 0; else if (q < 5120) lq = 1; else if (q < 5376) lq = 2;
    const int r  = q - starts[lq];
    const int Wq = dims[lq];
    const int gy = r / Wq, gx = r % Wq;
    const float vrxq = vr[(n * NLV + lq) * 2 + 0];
    const float vryq = vr[(n * NLV + lq) * 2 + 1];
    const float rx = (gx + 0.5f) / (vrxq * Wq);
    const float ry = (gy + 0.5f) / (vryq * Wq);

    const long row = (long)n * LEN + q;

    // softmax over this head's 16 logits (redundant across 8 d4 lanes)
    const float* awp = AW + row * 128 + h * 16;
    float a[16];
    float mx = -1e30f;
    #pragma unroll
    for (int i = 0; i < 16; ++i) { a[i] = awp[i]; mx = fmaxf(mx, a[i]); }
    float s = 0.f;
    #pragma unroll
    for (int i = 0; i < 16; ++i) { a[i] = __expf(a[i] - mx); s += a[i]; }
    const float inv = 1.f / s;

    const float* offp = OFF + row * 256 + h * 32;   // (lvl,p,2)

    float4 acc = {0.f, 0.f, 0.f, 0.f};
    #pragma unroll
    for (int lvl = 0; lvl < NLV; ++lvl) {
        const int Hl = dims[lvl];
        const int Wl = Hl;
        const float fW = (float)Wl;
        const int sb = starts[lvl];
        const float lx = rx * vr[(n * NLV + lvl) * 2 + 0];
        const float ly = ry * vr[(n * NLV + lvl) * 2 + 1];
        // base of this (n, level, head, d4) in float4 units
        const float4* vb = V4 + (((long)n * LEN + sb) * NH + h) * 8 + d4;
        #pragma unroll
        for (int p = 0; p < NPT; ++p) {
            const float ox = offp[lvl * 8 + p * 2 + 0];
            const float oy = offp[lvl * 8 + p * 2 + 1];
            // (lx + ox/Wl)*Wl - 0.5 == lx*Wl + ox - 0.5 exactly (Wl = 2^k)
            const float x = fmaf(lx, fW, ox) - 0.5f;
            const float y = fmaf(ly, fW, oy) - 0.5f;
            const float x0f = floorf(x), y0f = floorf(y);
            const int ix0 = (int)x0f, iy0 = (int)y0f;
            const float wx1 = x - x0f, wy1 = y - y0f;
            const float wx0 = 1.f - wx1, wy0 = 1.f - wy1;

            const bool vx0 = (ix0 >= 0)     && (ix0 < Wl);
            const bool vx1 = (ix0 + 1 >= 0) && (ix0 + 1 < Wl);
            const bool vy0 = (iy0 >= 0)     && (iy0 < Hl);
            const bool vy1 = (iy0 + 1 >= 0) && (iy0 + 1 < Hl);
            const int cx0 = min(max(ix0, 0), Wl - 1);
            const int cx1 = min(max(ix0 + 1, 0), Wl - 1);
            const int cy0 = min(max(iy0, 0), Hl - 1);
            const int cy1 = min(max(iy0 + 1, 0), Hl - 1);

            const float w00 = (vx0 && vy0) ? wx0 * wy0 : 0.f;
            const float w10 = (vx1 && vy0) ? wx1 * wy0 : 0.f;
            const float w01 = (vx0 && vy1) ? wx0 * wy1 : 0.f;
            const float w11 = (vx1 && vy1) ? wx1 * wy1 : 0.f;

            const float4 g00 = vb[(long)(cy0 * Wl + cx0) * (NH * 8)];
            const float4 g10 = vb[(long)(cy0 * Wl + cx1) * (NH * 8)];
            const float4 g01 = vb[(long)(cy1 * Wl + cx0) * (NH * 8)];
            const float4 g11 = vb[(long)(cy1 * Wl + cx1) * (NH * 8)];

            const float awv = a[lvl * 4 + p] * inv;
            acc.x += awv * (w00 * g00.x + w10 * g10.x + w01 * g01.x + w11 * g11.x);
            acc.y += awv * (w00 * g00.y + w10 * g10.y + w01 * g01.y + w11 * g11.y);
            acc.z += awv * (w00 * g00.z + w10 * g10.z + w01 * g01.z + w11 * g11.z);
            acc.w += awv * (w00 * g00.w + w10 * g10.w + w01 * g01.w + w11 * g11.w);
        }
    }
    ATT4[row * 64 + h * 8 + d4] = acc;
}

// ---------------------------------------------------------------------------
// out = LayerNorm(X + Y) * g + b ; one block (256 threads) per row.
// ---------------------------------------------------------------------------
__global__ __launch_bounds__(256) void add_ln_kernel(
    const float* __restrict__ X, const float* __restrict__ Y,
    const float* __restrict__ g, const float* __restrict__ b,
    float* __restrict__ OUT)
{
    const long row = blockIdx.x;
    const int  t   = threadIdx.x;
    const int lane = t & 63, wid = t >> 6;
    __shared__ float red[4];

    float v = X[row * DM + t] + Y[row * DM + t];

    float s = v;
    #pragma unroll
    for (int o = 32; o > 0; o >>= 1) s += __shfl_down(s, o, 64);
    if (lane == 0) red[wid] = s;
    __syncthreads();
    const float mean = (red[0] + red[1] + red[2] + red[3]) * (1.f / DM);
    __syncthreads();

    const float dv = v - mean;
    float s2 = dv * dv;
    #pragma unroll
    for (int o = 32; o > 0; o >>= 1) s2 += __shfl_down(s2, o, 64);
    if (lane == 0) red[wid] = s2;
    __syncthreads();
    const float var = (red[0] + red[1] + red[2] + red[3]) * (1.f / DM);

    OUT[row * DM + t] = dv * rsqrtf(var + 1e-5f) * g[t] + b[t];
}

// ---------------------------------------------------------------------------
extern "C" void kernel_launch(void* const* d_in, const int* in_sizes, int n_in,
                              void* d_out, int out_size, void* d_ws, size_t ws_size,
                              hipStream_t stream)
{
    const float* src = (const float*)d_in[0];
    const float* pos = (const float*)d_in[1];
    const float* vr  = (const float*)d_in[2];
    const float* Wv_   = (const float*)d_in[3];
    const float* bv_   = (const float*)d_in[4];
    const float* Woff_ = (const float*)d_in[5];
    const float* boff_ = (const float*)d_in[6];
    const float* Wa_   = (const float*)d_in[7];
    const float* ba_   = (const float*)d_in[8];
    const float* Wo_   = (const float*)d_in[9];
    const float* bo_   = (const float*)d_in[10];
    const float* g1_   = (const float*)d_in[11];
    const float* be1_  = (const float*)d_in[12];
    const float* Wl1_  = (const float*)d_in[13];
    const float* bl1_  = (const float*)d_in[14];
    const float* Wl2_  = (const float*)d_in[15];
    const float* bl2_  = (const float*)d_in[16];
    const float* g2_   = (const float*)d_in[17];
    const float* be2_  = (const float*)d_in[18];

    float* ws = (float*)d_ws;
    const long SZ = (long)MROWS * DM;
    float* V   = ws;
    float* OFF = V   + SZ;
    float* AW  = OFF + SZ;
    float* ATT = AW  + (long)MROWS * 128;
    float* AO  = ATT + SZ;
    float* FFN = AO  + SZ;
    float* XA  = FFN + (long)MROWS * DFFN;
    float* XB  = XA  + SZ;
    short* Wt  = (short*)(XB + SZ);

    const dim3 blk(256);
    const dim3 g256(DM / 64, MROWS / 64);
    const dim3 g128(128 / 64, MROWS / 64);
    const dim3 g1024(DFFN / 64, MROWS / 64);

    hipLaunchKernelGGL(transpose_convert_all, dim3(1472), blk, 0, stream,
                       Wv_, Woff_, Wa_, Wo_, Wl1_, Wl2_, Wt);

    const float* cur = src;
    for (int l = 0; l < 2; ++l) {
        const short* Wv   = Wt + (long)l * 753664 + 0;
        const short* Woff = Wt + (long)l * 753664 + 65536;
        const short* Wa   = Wt + (long)l * 753664 + 131072;
        const short* Wo   = Wt + (long)l * 753664 + 163840;
        const short* Wl1  = Wt + (long)l * 753664 + 229376;
        const short* Wl2  = Wt + (long)l * 753664 + 491520;
        const float* bv   = bv_   + (long)l * DM;
        const float* boff = boff_ + (long)l * 256;
        const float* ba   = ba_   + (long)l * 128;
        const float* bo   = bo_   + (long)l * DM;
        const float* g1   = g1_   + (long)l * DM;
        const float* be1  = be1_  + (long)l * DM;
        const float* bl1  = bl1_  + (long)l * DFFN;
        const float* bl2  = bl2_  + (long)l * DM;
        const float* g2   = g2_   + (long)l * DM;
        const float* be2  = be2_  + (long)l * DM;

        hipLaunchKernelGGL((gemm_mfma<0>), g256, blk, 0, stream,
                           cur, (const float*)nullptr, Wv, bv, V, MROWS, DM, DM);
        hipLaunchKernelGGL((gemm_mfma<0>), g256, blk, 0, stream,
                           cur, pos, Woff, boff, OFF, MROWS, 256, DM);
        hipLaunchKernelGGL((gemm_mfma<0>), g128, blk, 0, stream,
                           cur, pos, Wa, ba, AW, MROWS, 128, DM);
        hipLaunchKernelGGL(deform_attn_v2, dim3(MROWS / 4), blk, 0, stream,
                           (const float4*)V, OFF, AW, vr, (float4*)ATT);
        hipLaunchKernelGGL((gemm_mfma<0>), g256, blk, 0, stream,
                           ATT, (const float*)nullptr, Wo, bo, AO, MROWS, DM, DM);
        hipLaunchKernelGGL(add_ln_kernel, dim3(MROWS), blk, 0, stream,
                           cur, AO, g1, be1, XA);
        hipLaunchKernelGGL((gemm_mfma<1>), g1024, blk, 0, stream,
                           XA, (const float*)nullptr, Wl1, bl1, FFN, MROWS, DFFN, DM);
        hipLaunchKernelGGL((gemm_mfma<0>), g256, blk, 0, stream,
                           FFN, (const float*)nullptr, Wl2, bl2, AO, MROWS, DM, DFFN);
        float* dst = (l == 1) ? (float*)d_out : XB;
        hipLaunchKernelGGL(add_ln_kernel, dim3(MROWS), blk, 0, stream,
                           XA, AO, g2, be2, dst);
        cur = dst;
    }
}

// Round 4
// 387.309 us; speedup vs baseline: 2.4416x; 1.0553x over previous
//
#include <hip/hip_runtime.h>
#include <math.h>

#define LEN   5440
#define NB    2
#define MROWS (NB * LEN)   // 10880
#define DM    256
#define NH    8
#define HD    32
#define NLV   4
#define NPT   4
#define DFFN  1024

typedef __attribute__((ext_vector_type(8))) short bf16x8;
typedef __attribute__((ext_vector_type(4))) short bf16x4;
typedef __attribute__((ext_vector_type(4))) float f32x4;

__device__ __forceinline__ short f2bf(float f) {
    union { float f; unsigned u; } cv; cv.f = f;
    unsigned r = cv.u + 0x7fffu + ((cv.u >> 16) & 1u);   // RNE
    return (short)(r >> 16);
}

// ---------------------------------------------------------------------------
// One-shot: transpose+convert all 12 weight matrices fp32 [K][N] -> bf16 [N][K].
// Per-layer short offsets: Wv@0 | Woff@65536 | Wa@131072 (contiguous 640xK=256
// for the fused QKV gemm), Wo@163840, Wl1@229376, Wl2@491520; layer stride 753664.
// ---------------------------------------------------------------------------
__global__ __launch_bounds__(256) void transpose_convert_all(
    const float* __restrict__ Wv,  const float* __restrict__ Woff,
    const float* __restrict__ Wa,  const float* __restrict__ Wo,
    const float* __restrict__ Wl1, const float* __restrict__ Wl2,
    short* __restrict__ out)
{
    int bx = blockIdx.x;
    int l  = bx / 736;
    int t  = bx % 736;
    const float* src; int K, N; long doff;
    if      (t < 64)  { src = Wv;   K = 256;  N = 256;  doff = 0;      }
    else if (t < 128) { src = Woff; K = 256;  N = 256;  doff = 65536;  t -= 64;  }
    else if (t < 160) { src = Wa;   K = 256;  N = 128;  doff = 131072; t -= 128; }
    else if (t < 224) { src = Wo;   K = 256;  N = 256;  doff = 163840; t -= 160; }
    else if (t < 480) { src = Wl1;  K = 256;  N = 1024; doff = 229376; t -= 224; }
    else              { src = Wl2;  K = 1024; N = 256;  doff = 491520; t -= 480; }
    src += (long)l * K * N;
    short* dst = out + (long)l * 753664 + doff;

    const int ntx = N / 32;
    const int n0 = (t % ntx) * 32, k0 = (t / ntx) * 32;

    __shared__ short T[32][33];
    const int tid = threadIdx.x;
    {
        const int n = tid & 31, kq = tid >> 5;
        #pragma unroll
        for (int i = 0; i < 4; ++i) {
            int k = kq * 4 + i;
            T[n][k] = f2bf(src[(long)(k0 + k) * N + n0 + n]);
        }
    }
    __syncthreads();
    {
        const int k = tid & 31, nq = tid >> 5;
        #pragma unroll
        for (int i = 0; i < 4; ++i) {
            int n = nq * 4 + i;
            dst[(long)(n0 + n) * K + k0 + k] = T[n][k];
        }
    }
}

// ---------------------------------------------------------------------------
// src -> bf16(src), bf16(src+pos)
// ---------------------------------------------------------------------------
__global__ __launch_bounds__(256) void convert_src(
    const float4* __restrict__ s4, const float4* __restrict__ p4,
    bf16x4* __restrict__ curb, bf16x4* __restrict__ qb)
{
    const int i = blockIdx.x * 256 + threadIdx.x;   // < MROWS*DM/4
    float4 s = s4[i], p = p4[i];
    bf16x4 c, q;
    c[0] = f2bf(s.x); c[1] = f2bf(s.y); c[2] = f2bf(s.z); c[3] = f2bf(s.w);
    q[0] = f2bf(s.x + p.x); q[1] = f2bf(s.y + p.y);
    q[2] = f2bf(s.z + p.z); q[3] = f2bf(s.w + p.w);
    curb[i] = c; qb[i] = q;
}

// ---------------------------------------------------------------------------
// MFMA bf16 GEMM core. A bf16 [M][K], Wt bf16 [N][K]. Tile 64x64, BK=64,
// 4 waves as 2x2 quadrants, 2 k-steps/iter. LDS row stride 72 shorts
// (2-way bank aliasing on b128 read & write = free, m136).
// ---------------------------------------------------------------------------
template <int RELU, int OBF>
__device__ __forceinline__ void gemm_core(
    short* As, short* Bs,
    const short* __restrict__ A, const short* __restrict__ Wt,
    const float* __restrict__ bias, float* Cf, short* Cb,
    int ldc, int m0, int wrow0, int ccol0, int K)
{
    const int t    = threadIdx.x;
    const int wave = t >> 6, lane = t & 63;
    const int wm   = (wave & 1) * 32;
    const int wn   = (wave >> 1) * 32;
    const int srow = t >> 3;            // 0..31
    const int skof = (t & 7) * 8;       // 0..56
    const int lm   = lane & 15;
    const int lk   = (lane >> 4) * 8;

    f32x4 acc[2][2] = {};

    for (int k0 = 0; k0 < K; k0 += 64) {
        #pragma unroll
        for (int c = 0; c < 2; ++c) {
            const int row = srow + c * 32;
            *(bf16x8*)(&As[row * 72 + skof]) =
                *(const bf16x8*)(A + (long)(m0 + row) * K + k0 + skof);
            *(bf16x8*)(&Bs[row * 72 + skof]) =
                *(const bf16x8*)(Wt + (long)(wrow0 + row) * K + k0 + skof);
        }
        __syncthreads();

        #pragma unroll
        for (int kk = 0; kk < 2; ++kk) {
            const int ko = kk * 32 + lk;
            bf16x8 af0 = *(const bf16x8*)(&As[(wm + lm)      * 72 + ko]);
            bf16x8 af1 = *(const bf16x8*)(&As[(wm + 16 + lm) * 72 + ko]);
            bf16x8 bf0 = *(const bf16x8*)(&Bs[(wn + lm)      * 72 + ko]);
            bf16x8 bf1 = *(const bf16x8*)(&Bs[(wn + 16 + lm) * 72 + ko]);
            acc[0][0] = __builtin_amdgcn_mfma_f32_16x16x32_bf16(af0, bf0, acc[0][0], 0, 0, 0);
            acc[0][1] = __builtin_amdgcn_mfma_f32_16x16x32_bf16(af0, bf1, acc[0][1], 0, 0, 0);
            acc[1][0] = __builtin_amdgcn_mfma_f32_16x16x32_bf16(af1, bf0, acc[1][0], 0, 0, 0);
            acc[1][1] = __builtin_amdgcn_mfma_f32_16x16x32_bf16(af1, bf1, acc[1][1], 0, 0, 0);
        }
        __syncthreads();
    }

    const int col = lane & 15;
    const int rq  = (lane >> 4) * 4;
    #pragma unroll
    for (int mi = 0; mi < 2; ++mi) {
        #pragma unroll
        for (int nj = 0; nj < 2; ++nj) {
            const int gn = ccol0 + wn + nj * 16 + col;
            const float bb = bias[gn];
            #pragma unroll
            for (int r = 0; r < 4; ++r) {
                const int gm = m0 + wm + mi * 16 + rq + r;
                float v = acc[mi][nj][r] + bb;
                if (RELU) v = fmaxf(v, 0.f);
                if (OBF) Cb[(long)gm * ldc + gn] = f2bf(v);
                else     Cf[(long)gm * ldc + gn] = v;
            }
        }
    }
}

template <int RELU, int OBF>
__global__ __launch_bounds__(256) void gemm_bb(
    const short* __restrict__ A, const short* __restrict__ Wt,
    const float* __restrict__ bias, float* Cf, short* Cb, int N, int K)
{
    __shared__ __align__(16) short As[64 * 72];
    __shared__ __align__(16) short Bs[64 * 72];
    gemm_core<RELU, OBF>(As, Bs, A, Wt, bias, Cf, Cb, N,
                         blockIdx.y * 64, blockIdx.x * 64, blockIdx.x * 64, K);
}

// Fused query-side GEMM: [V | OFF | AW] over N=640 (Wv|Woff|Wa rows contiguous).
__global__ __launch_bounds__(256) void gemm_fused_qkv(
    const short* __restrict__ curb, const short* __restrict__ qb,
    const short* __restrict__ Wt,   // layer base (rows 0..639, K=256)
    const float* __restrict__ bv, const float* __restrict__ boff,
    const float* __restrict__ ba,
    float* __restrict__ V, float* __restrict__ OFF, float* __restrict__ AW)
{
    __shared__ __align__(16) short As[64 * 72];
    __shared__ __align__(16) short Bs[64 * 72];
    const int n0 = blockIdx.x * 64;   // 0..576
    const short* A; const float* bias; float* C; int ldc, ccol;
    if (n0 < 256)      { A = curb; bias = bv;   C = V;   ldc = 256; ccol = n0; }
    else if (n0 < 512) { A = qb;   bias = boff; C = OFF; ldc = 256; ccol = n0 - 256; }
    else               { A = qb;   bias = ba;   C = AW;  ldc = 128; ccol = n0 - 512; }
    gemm_core<0, 0>(As, Bs, A, Wt, bias, C, (short*)nullptr, ldc,
                    blockIdx.y * 64, n0, ccol, 256);
}

// ---------------------------------------------------------------------------
// Deformable attention sampling v2 (one wave/query; lane = h*8+d4, float4
// gathers). Output written as bf16 (feeds the Wo GEMM).
// ---------------------------------------------------------------------------
__global__ __launch_bounds__(256) void deform_attn_v2(
    const float4* __restrict__ V4,   // (NB, LEN, NH, 8) float4
    const float* __restrict__ OFF,   // (MROWS, 256)
    const float* __restrict__ AW,    // (MROWS, 128)
    const float* __restrict__ vr,    // (NB, NLV, 2)
    bf16x4* __restrict__ ATTb)       // (MROWS, 64) bf16x4
{
    const int starts[5] = {0, 4096, 5120, 5376, 5440};
    const int dims[4]   = {64, 32, 16, 8};

    const int wave = threadIdx.x >> 6;
    const int lane = threadIdx.x & 63;
    const int h    = lane >> 3;
    const int d4   = lane & 7;

    const int gq = blockIdx.x * 4 + wave;
    const int n  = gq / LEN;
    const int q  = gq % LEN;

    int lq = 3;
    if (q < 4096) lq = 0; else if (q < 5120) lq = 1; else if (q < 5376) lq = 2;
    const int r  = q - starts[lq];
    const int Wq = dims[lq];
    const int gy = r / Wq, gx = r % Wq;
    const float vrxq = vr[(n * NLV + lq) * 2 + 0];
    const float vryq = vr[(n * NLV + lq) * 2 + 1];
    const float rx = (gx + 0.5f) / (vrxq * Wq);
    const float ry = (gy + 0.5f) / (vryq * Wq);

    const long row = (long)n * LEN + q;

    const float* awp = AW + row * 128 + h * 16;
    float a[16];
    float mx = -1e30f;
    #pragma unroll
    for (int i = 0; i < 16; ++i) { a[i] = awp[i]; mx = fmaxf(mx, a[i]); }
    float s = 0.f;
    #pragma unroll
    for (int i = 0; i < 16; ++i) { a[i] = __expf(a[i] - mx); s += a[i]; }
    const float inv = 1.f / s;

    const float* offp = OFF + row * 256 + h * 32;

    float4 acc = {0.f, 0.f, 0.f, 0.f};
    #pragma unroll
    for (int lvl = 0; lvl < NLV; ++lvl) {
        const int Hl = dims[lvl];
        const int Wl = Hl;
        const float fW = (float)Wl;
        const int sb = starts[lvl];
        const float lx = rx * vr[(n * NLV + lvl) * 2 + 0];
        const float ly = ry * vr[(n * NLV + lvl) * 2 + 1];
        const float4* vb = V4 + (((long)n * LEN + sb) * NH + h) * 8 + d4;
        #pragma unroll
        for (int p = 0; p < NPT; ++p) {
            const float ox = offp[lvl * 8 + p * 2 + 0];
            const float oy = offp[lvl * 8 + p * 2 + 1];
            const float x = fmaf(lx, fW, ox) - 0.5f;
            const float y = fmaf(ly, fW, oy) - 0.5f;
            const float x0f = floorf(x), y0f = floorf(y);
            const int ix0 = (int)x0f, iy0 = (int)y0f;
            const float wx1 = x - x0f, wy1 = y - y0f;
            const float wx0 = 1.f - wx1, wy0 = 1.f - wy1;

            const bool vx0 = (ix0 >= 0)     && (ix0 < Wl);
            const bool vx1 = (ix0 + 1 >= 0) && (ix0 + 1 < Wl);
            const bool vy0 = (iy0 >= 0)     && (iy0 < Hl);
            const bool vy1 = (iy0 + 1 >= 0) && (iy0 + 1 < Hl);
            const int cx0 = min(max(ix0, 0), Wl - 1);
            const int cx1 = min(max(ix0 + 1, 0), Wl - 1);
            const int cy0 = min(max(iy0, 0), Hl - 1);
            const int cy1 = min(max(iy0 + 1, 0), Hl - 1);

            const float w00 = (vx0 && vy0) ? wx0 * wy0 : 0.f;
            const float w10 = (vx1 && vy0) ? wx1 * wy0 : 0.f;
            const float w01 = (vx0 && vy1) ? wx0 * wy1 : 0.f;
            const float w11 = (vx1 && vy1) ? wx1 * wy1 : 0.f;

            const float4 g00 = vb[(long)(cy0 * Wl + cx0) * (NH * 8)];
            const float4 g10 = vb[(long)(cy0 * Wl + cx1) * (NH * 8)];
            const float4 g01 = vb[(long)(cy1 * Wl + cx0) * (NH * 8)];
            const float4 g11 = vb[(long)(cy1 * Wl + cx1) * (NH * 8)];

            const float awv = a[lvl * 4 + p] * inv;
            acc.x += awv * (w00 * g00.x + w10 * g10.x + w01 * g01.x + w11 * g11.x);
            acc.y += awv * (w00 * g00.y + w10 * g10.y + w01 * g01.y + w11 * g11.y);
            acc.z += awv * (w00 * g00.z + w10 * g10.z + w01 * g01.z + w11 * g11.z);
            acc.w += awv * (w00 * g00.w + w10 * g10.w + w01 * g01.w + w11 * g11.w);
        }
    }
    bf16x4 ob;
    ob[0] = f2bf(acc.x); ob[1] = f2bf(acc.y);
    ob[2] = f2bf(acc.z); ob[3] = f2bf(acc.w);
    ATTb[row * 64 + h * 8 + d4] = ob;
}

// ---------------------------------------------------------------------------
// LN(X+Y)*g+b with optional fp32 / bf16 / bf16(+pos) outputs.
// ---------------------------------------------------------------------------
__global__ __launch_bounds__(256) void add_ln_kernel(
    const float* __restrict__ X, const float* __restrict__ Y,
    const float* __restrict__ g, const float* __restrict__ b,
    float* __restrict__ outf, short* __restrict__ outb,
    short* __restrict__ outq, const float* __restrict__ pos)
{
    const long row = blockIdx.x;
    const int  t   = threadIdx.x;
    const int lane = t & 63, wid = t >> 6;
    __shared__ float red[4];

    float v = X[row * DM + t] + Y[row * DM + t];

    float s = v;
    #pragma unroll
    for (int o = 32; o > 0; o >>= 1) s += __shfl_down(s, o, 64);
    if (lane == 0) red[wid] = s;
    __syncthreads();
    const float mean = (red[0] + red[1] + red[2] + red[3]) * (1.f / DM);
    __syncthreads();

    const float dv = v - mean;
    float s2 = dv * dv;
    #pragma unroll
    for (int o = 32; o > 0; o >>= 1) s2 += __shfl_down(s2, o, 64);
    if (lane == 0) red[wid] = s2;
    __syncthreads();
    const float var = (red[0] + red[1] + red[2] + red[3]) * (1.f / DM);

    const float r = dv * rsqrtf(var + 1e-5f) * g[t] + b[t];
    if (outf) outf[row * DM + t] = r;
    if (outb) outb[row * DM + t] = f2bf(r);
    if (outq) outq[row * DM + t] = f2bf(r + pos[row * DM + t]);
}

// ---------------------------------------------------------------------------
extern "C" void kernel_launch(void* const* d_in, const int* in_sizes, int n_in,
                              void* d_out, int out_size, void* d_ws, size_t ws_size,
                              hipStream_t stream)
{
    const float* src = (const float*)d_in[0];
    const float* pos = (const float*)d_in[1];
    const float* vr  = (const float*)d_in[2];
    const float* Wv_   = (const float*)d_in[3];
    const float* bv_   = (const float*)d_in[4];
    const float* Woff_ = (const float*)d_in[5];
    const float* boff_ = (const float*)d_in[6];
    const float* Wa_   = (const float*)d_in[7];
    const float* ba_   = (const float*)d_in[8];
    const float* Wo_   = (const float*)d_in[9];
    const float* bo_   = (const float*)d_in[10];
    const float* g1_   = (const float*)d_in[11];
    const float* be1_  = (const float*)d_in[12];
    const float* Wl1_  = (const float*)d_in[13];
    const float* bl1_  = (const float*)d_in[14];
    const float* Wl2_  = (const float*)d_in[15];
    const float* bl2_  = (const float*)d_in[16];
    const float* g2_   = (const float*)d_in[17];
    const float* be2_  = (const float*)d_in[18];

    const long SZ = (long)MROWS * DM;        // 2,785,280 elements
    float* ws = (float*)d_ws;
    float* V    = ws;                         // f32 M x 256
    float* OFF  = V   + SZ;                   // f32 M x 256
    float* AW   = OFF + SZ;                   // f32 M x 128
    float* AO   = AW  + (long)MROWS * 128;    // f32 M x 256 (Wo out, FFN2 out)
    float* XA   = AO  + SZ;                   // f32 M x 256 (LN1 out)
    float* XB   = XA  + SZ;                   // f32 M x 256 (LN2 out, layer0)
    short* curb = (short*)(XB + SZ);          // bf16 M x 256
    short* qb   = curb + SZ;                  // bf16 M x 256
    short* ATTb = qb   + SZ;                  // bf16 M x 256
    short* XAb  = ATTb + SZ;                  // bf16 M x 256
    short* FFNb = XAb  + SZ;                  // bf16 M x 1024
    short* Wt   = FFNb + (long)MROWS * DFFN;  // 2 x 753664 bf16 weights

    const dim3 blk(256);
    const int GY = MROWS / 64;                // 170

    hipLaunchKernelGGL(transpose_convert_all, dim3(1472), blk, 0, stream,
                       Wv_, Woff_, Wa_, Wo_, Wl1_, Wl2_, Wt);
    hipLaunchKernelGGL(convert_src, dim3(SZ / 4 / 256), blk, 0, stream,
                       (const float4*)src, (const float4*)pos,
                       (bf16x4*)curb, (bf16x4*)qb);

    const float* cur = src;
    for (int l = 0; l < 2; ++l) {
        const short* Wbase = Wt + (long)l * 753664;
        const float* bv   = bv_   + (long)l * DM;
        const float* boff = boff_ + (long)l * 256;
        const float* ba   = ba_   + (long)l * 128;
        const float* bo   = bo_   + (long)l * DM;
        const float* g1   = g1_   + (long)l * DM;
        const float* be1  = be1_  + (long)l * DM;
        const float* bl1  = bl1_  + (long)l * DFFN;
        const float* bl2  = bl2_  + (long)l * DM;
        const float* g2   = g2_   + (long)l * DM;
        const float* be2  = be2_  + (long)l * DM;

        // [V | OFF | AW] = [curb | qb] @ [Wv|Woff|Wa]
        hipLaunchKernelGGL(gemm_fused_qkv, dim3(10, GY), blk, 0, stream,
                           curb, qb, Wbase, bv, boff, ba, V, OFF, AW);
        hipLaunchKernelGGL(deform_attn_v2, dim3(MROWS / 4), blk, 0, stream,
                           (const float4*)V, OFF, AW, vr, (bf16x4*)ATTb);
        // AO = ATT @ Wo + bo
        hipLaunchKernelGGL((gemm_bb<0, 0>), dim3(4, GY), blk, 0, stream,
                           ATTb, Wbase + 163840, bo, AO, (short*)nullptr, 256, 256);
        // XA = LN(cur + AO); also bf16 copy for FFN1
        hipLaunchKernelGGL(add_ln_kernel, dim3(MROWS), blk, 0, stream,
                           cur, AO, g1, be1, XA, XAb, (short*)nullptr,
                           (const float*)nullptr);
        // FFNb = relu(XA @ Wl1 + bl1)  (bf16 out)
        hipLaunchKernelGGL((gemm_bb<1, 1>), dim3(16, GY), blk, 0, stream,
                           XAb, Wbase + 229376, bl1, (float*)nullptr, FFNb, 1024, 256);
        // AO = FFNb @ Wl2 + bl2
        hipLaunchKernelGGL((gemm_bb<0, 0>), dim3(4, GY), blk, 0, stream,
                           FFNb, Wbase + 491520, bl2, AO, (short*)nullptr, 256, 1024);
        // out = LN(XA + AO); layer0 also emits bf16 cur and bf16(cur+pos)
        if (l == 0) {
            hipLaunchKernelGGL(add_ln_kernel, dim3(MROWS), blk, 0, stream,
                               XA, AO, g2, be2, XB, curb, qb, pos);
            cur = XB;
        } else {
            hipLaunchKernelGGL(add_ln_kernel, dim3(MROWS), blk, 0, stream,
                               XA, AO, g2, be2, (float*)d_out, (short*)nullptr,
                               (short*)nullptr, (const float*)nullptr);
        }
    }
}

// Round 5
// 373.952 us; speedup vs baseline: 2.5288x; 1.0357x over previous
//
#include <hip/hip_runtime.h>
#include <math.h>

#define LEN   5440
#define NB    2
#define MROWS (NB * LEN)   // 10880
#define DM    256
#define NH    8
#define HD    32
#define NLV   4
#define NPT   4
#define DFFN  1024

typedef __attribute__((ext_vector_type(8))) short bf16x8;
typedef __attribute__((ext_vector_type(4))) short bf16x4;
typedef __attribute__((ext_vector_type(4))) float f32x4;

__device__ __forceinline__ short f2bf(float f) {
    union { float f; unsigned u; } cv; cv.f = f;
    unsigned r = cv.u + 0x7fffu + ((cv.u >> 16) & 1u);   // RNE
    return (short)(r >> 16);
}

// async global->LDS, 16B per lane; LDS dest = wave-uniform base + lane*16
__device__ __forceinline__ void gload_lds(const short* g, short* l) {
    __builtin_amdgcn_global_load_lds(
        (const __attribute__((address_space(1))) void*)g,
        (__attribute__((address_space(3))) void*)l, 16, 0, 0);
}

// ---------------------------------------------------------------------------
// One-shot: transpose+convert all 12 weight matrices fp32 [K][N] -> bf16 [N][K].
// Per-layer short offsets: Wv@0 | Woff@65536 | Wa@131072 (contiguous 640 rows,
// K=256, for fused qkv), Wo@163840, Wl1@229376, Wl2@491520; layer stride 753664.
// ---------------------------------------------------------------------------
__global__ __launch_bounds__(256) void transpose_convert_all(
    const float* __restrict__ Wv,  const float* __restrict__ Woff,
    const float* __restrict__ Wa,  const float* __restrict__ Wo,
    const float* __restrict__ Wl1, const float* __restrict__ Wl2,
    short* __restrict__ out)
{
    int bx = blockIdx.x;
    int l  = bx / 736;
    int t  = bx % 736;
    const float* src; int K, N; long doff;
    if      (t < 64)  { src = Wv;   K = 256;  N = 256;  doff = 0;      }
    else if (t < 128) { src = Woff; K = 256;  N = 256;  doff = 65536;  t -= 64;  }
    else if (t < 160) { src = Wa;   K = 256;  N = 128;  doff = 131072; t -= 128; }
    else if (t < 224) { src = Wo;   K = 256;  N = 256;  doff = 163840; t -= 160; }
    else if (t < 480) { src = Wl1;  K = 256;  N = 1024; doff = 229376; t -= 224; }
    else              { src = Wl2;  K = 1024; N = 256;  doff = 491520; t -= 480; }
    src += (long)l * K * N;
    short* dst = out + (long)l * 753664 + doff;

    const int ntx = N / 32;
    const int n0 = (t % ntx) * 32, k0 = (t / ntx) * 32;

    __shared__ short T[32][33];
    const int tid = threadIdx.x;
    {
        const int n = tid & 31, kq = tid >> 5;
        #pragma unroll
        for (int i = 0; i < 4; ++i) {
            int k = kq * 4 + i;
            T[n][k] = f2bf(src[(long)(k0 + k) * N + n0 + n]);
        }
    }
    __syncthreads();
    {
        const int k = tid & 31, nq = tid >> 5;
        #pragma unroll
        for (int i = 0; i < 4; ++i) {
            int n = nq * 4 + i;
            dst[(long)(n0 + n) * K + k0 + k] = T[n][k];
        }
    }
}

// ---------------------------------------------------------------------------
// src -> bf16(src), bf16(src+pos)
// ---------------------------------------------------------------------------
__global__ __launch_bounds__(256) void convert_src(
    const float4* __restrict__ s4, const float4* __restrict__ p4,
    bf16x4* __restrict__ curb, bf16x4* __restrict__ qb)
{
    const int i = blockIdx.x * 256 + threadIdx.x;
    float4 s = s4[i], p = p4[i];
    bf16x4 c, q;
    c[0] = f2bf(s.x); c[1] = f2bf(s.y); c[2] = f2bf(s.z); c[3] = f2bf(s.w);
    q[0] = f2bf(s.x + p.x); q[1] = f2bf(s.y + p.y);
    q[2] = f2bf(s.z + p.z); q[3] = f2bf(s.w + p.w);
    curb[i] = c; qb[i] = q;
}

// ---------------------------------------------------------------------------
// m97-structure MFMA GEMM: 128 x BN tile, BK=32, global_load_lds staging.
// LDS layout [rows][32k] unpadded (64 B/row); chunk slot XOR-swizzled:
//   slot(m, chunk) = chunk ^ (m&3) ^ ((m>>2)&1)
// -> ds_read_b128 fragment reads are 2-way bank-aliased (free, m136).
// 4 waves: wave w owns rows (w&1)*64, cols (w>>1)*(BN/2); 4 x NF subtiles.
// ---------------------------------------------------------------------------
template <int BN, int RELU, int OBF>
__device__ __forceinline__ void gemm_core128(
    short* As, short* Bs,
    const short* __restrict__ A, const short* __restrict__ Wt,
    const float* __restrict__ bias, float* __restrict__ Cf,
    short* __restrict__ Cb,
    int ldc, int m0, int wrow0, int ccol0, int K)
{
    constexpr int NF = BN / 32;            // B frags per wave: 2 or 4
    const int t    = threadIdx.x;
    const int wave = t >> 6, lane = t & 63;
    const int wm   = (wave & 1) * 64;
    const int wn   = (wave >> 1) * (BN / 2);
    const int lm   = lane & 15;
    const int chkg = lane >> 4;            // frag k-chunk 0..3 (k = chkg*8)
    const int r_l  = lane >> 2;            // staging row-in-16
    const int slot = lane & 3;
    const int cg   = slot ^ (r_l & 3) ^ ((r_l >> 2) & 1);  // global chunk to fetch
    const int pos  = chkg ^ (lm & 3) ^ ((lm >> 2) & 1);    // LDS slot for frag read

    f32x4 acc[4][NF] = {};

    const int rb0 = wave * 16;

    for (int k0 = 0; k0 < K; k0 += 32) {
        // ---- stage A (128 rows): 2 instrs/wave ----
        #pragma unroll
        for (int j = 0; j < 2; ++j) {
            const int rb = j * 64 + rb0;
            gload_lds(A + (long)(m0 + rb + r_l) * K + k0 + cg * 8, &As[rb * 32]);
        }
        // ---- stage B (BN rows): BN/64 instrs/wave ----
        #pragma unroll
        for (int j = 0; j < BN / 64; ++j) {
            const int rb = j * 64 + rb0;
            gload_lds(Wt + (long)(wrow0 + rb + r_l) * K + k0 + cg * 8, &Bs[rb * 32]);
        }
        __syncthreads();

        bf16x8 af[4], bfv[NF];
        #pragma unroll
        for (int s = 0; s < 4; ++s)
            af[s] = *(const bf16x8*)(&As[(wm + s * 16 + lm) * 32 + pos * 8]);
        #pragma unroll
        for (int u = 0; u < NF; ++u)
            bfv[u] = *(const bf16x8*)(&Bs[(wn + u * 16 + lm) * 32 + pos * 8]);
        #pragma unroll
        for (int s = 0; s < 4; ++s)
            #pragma unroll
            for (int u = 0; u < NF; ++u)
                acc[s][u] = __builtin_amdgcn_mfma_f32_16x16x32_bf16(
                    af[s], bfv[u], acc[s][u], 0, 0, 0);
        __syncthreads();
    }

    // ---- epilogue: D col=lane&15, row=(lane>>4)*4+r ----
    const int col = lane & 15;
    const int rq  = (lane >> 4) * 4;
    #pragma unroll
    for (int s = 0; s < 4; ++s) {
        #pragma unroll
        for (int u = 0; u < NF; ++u) {
            const int gn = ccol0 + wn + u * 16 + col;
            const float bb = bias[gn];
            #pragma unroll
            for (int r = 0; r < 4; ++r) {
                const int gm = m0 + wm + s * 16 + rq + r;
                float v = acc[s][u][r] + bb;
                if (RELU) v = fmaxf(v, 0.f);
                if (OBF) Cb[(long)gm * ldc + gn] = f2bf(v);
                else     Cf[(long)gm * ldc + gn] = v;
            }
        }
    }
}

template <int BN, int RELU, int OBF>
__global__ __launch_bounds__(256) void gemm128(
    const short* __restrict__ A, const short* __restrict__ Wt,
    const float* __restrict__ bias, float* Cf, short* Cb, int ldc, int K)
{
    __shared__ __align__(16) short As[128 * 32];
    __shared__ __align__(16) short Bs[BN * 32];
    gemm_core128<BN, RELU, OBF>(As, Bs, A, Wt, bias, Cf, Cb, ldc,
                                blockIdx.y * 128, blockIdx.x * BN,
                                blockIdx.x * BN, K);
}

// Fused query-side GEMM: [V | OFF | AW] over N=640 (Wv|Woff|Wa rows contiguous).
__global__ __launch_bounds__(256) void gemm_qkv128(
    const short* __restrict__ curb, const short* __restrict__ qb,
    const short* __restrict__ Wt, const float* __restrict__ bv,
    const float* __restrict__ boff, const float* __restrict__ ba,
    float* __restrict__ V, float* __restrict__ OFF, float* __restrict__ AW)
{
    __shared__ __align__(16) short As[128 * 32];
    __shared__ __align__(16) short Bs[128 * 32];
    const int n0 = blockIdx.x * 128;   // 0,128,256,384,512
    const short* A; const float* bias; float* C; int ldc, ccol;
    if (n0 < 256)      { A = curb; bias = bv;   C = V;   ldc = 256; ccol = n0; }
    else if (n0 < 512) { A = qb;   bias = boff; C = OFF; ldc = 256; ccol = n0 - 256; }
    else               { A = qb;   bias = ba;   C = AW;  ldc = 128; ccol = n0 - 512; }
    gemm_core128<128, 0, 0>(As, Bs, A, Wt, bias, C, (short*)nullptr, ldc,
                            blockIdx.y * 128, n0, ccol, 256);
}

// ---------------------------------------------------------------------------
// Deformable attention sampling v2 (one wave/query; lane = h*8+d4, float4
// gathers). Output bf16 (feeds Wo GEMM).
// ---------------------------------------------------------------------------
__global__ __launch_bounds__(256) void deform_attn_v2(
    const float4* __restrict__ V4,   // (NB, LEN, NH, 8) float4
    const float* __restrict__ OFF,   // (MROWS, 256)
    const float* __restrict__ AW,    // (MROWS, 128)
    const float* __restrict__ vr,    // (NB, NLV, 2)
    bf16x4* __restrict__ ATTb)       // (MROWS, 64) bf16x4
{
    const int starts[5] = {0, 4096, 5120, 5376, 5440};
    const int dims[4]   = {64, 32, 16, 8};

    const int wave = threadIdx.x >> 6;
    const int lane = threadIdx.x & 63;
    const int h    = lane >> 3;
    const int d4   = lane & 7;

    const int gq = blockIdx.x * 4 + wave;
    const int n  = gq / LEN;
    const int q  = gq % LEN;

    int lq = 3;
    if (q < 4096) lq = 0; else if (q < 5120) lq = 1; else if (q < 5376) lq = 2;
    const int r  = q - starts[lq];
    const int Wq = dims[lq];
    const int gy = r / Wq, gx = r % Wq;
    const float vrxq = vr[(n * NLV + lq) * 2 + 0];
    const float vryq = vr[(n * NLV + lq) * 2 + 1];
    const float rx = (gx + 0.5f) / (vrxq * Wq);
    const float ry = (gy + 0.5f) / (vryq * Wq);

    const long row = (long)n * LEN + q;

    const float* awp = AW + row * 128 + h * 16;
    float a[16];
    float mx = -1e30f;
    #pragma unroll
    for (int i = 0; i < 16; ++i) { a[i] = awp[i]; mx = fmaxf(mx, a[i]); }
    float s = 0.f;
    #pragma unroll
    for (int i = 0; i < 16; ++i) { a[i] = __expf(a[i] - mx); s += a[i]; }
    const float inv = 1.f / s;

    const float* offp = OFF + row * 256 + h * 32;

    float4 acc = {0.f, 0.f, 0.f, 0.f};
    #pragma unroll
    for (int lvl = 0; lvl < NLV; ++lvl) {
        const int Hl = dims[lvl];
        const int Wl = Hl;
        const float fW = (float)Wl;
        const int sb = starts[lvl];
        const float lx = rx * vr[(n * NLV + lvl) * 2 + 0];
        const float ly = ry * vr[(n * NLV + lvl) * 2 + 1];
        const float4* vb = V4 + (((long)n * LEN + sb) * NH + h) * 8 + d4;
        #pragma unroll
        for (int p = 0; p < NPT; ++p) {
            const float ox = offp[lvl * 8 + p * 2 + 0];
            const float oy = offp[lvl * 8 + p * 2 + 1];
            const float x = fmaf(lx, fW, ox) - 0.5f;
            const float y = fmaf(ly, fW, oy) - 0.5f;
            const float x0f = floorf(x), y0f = floorf(y);
            const int ix0 = (int)x0f, iy0 = (int)y0f;
            const float wx1 = x - x0f, wy1 = y - y0f;
            const float wx0 = 1.f - wx1, wy0 = 1.f - wy1;

            const bool vx0 = (ix0 >= 0)     && (ix0 < Wl);
            const bool vx1 = (ix0 + 1 >= 0) && (ix0 + 1 < Wl);
            const bool vy0 = (iy0 >= 0)     && (iy0 < Hl);
            const bool vy1 = (iy0 + 1 >= 0) && (iy0 + 1 < Hl);
            const int cx0 = min(max(ix0, 0), Wl - 1);
            const int cx1 = min(max(ix0 + 1, 0), Wl - 1);
            const int cy0 = min(max(iy0, 0), Hl - 1);
            const int cy1 = min(max(iy0 + 1, 0), Hl - 1);

            const float w00 = (vx0 && vy0) ? wx0 * wy0 : 0.f;
            const float w10 = (vx1 && vy0) ? wx1 * wy0 : 0.f;
            const float w01 = (vx0 && vy1) ? wx0 * wy1 : 0.f;
            const float w11 = (vx1 && vy1) ? wx1 * wy1 : 0.f;

            const float4 g00 = vb[(long)(cy0 * Wl + cx0) * (NH * 8)];
            const float4 g10 = vb[(long)(cy0 * Wl + cx1) * (NH * 8)];
            const float4 g01 = vb[(long)(cy1 * Wl + cx0) * (NH * 8)];
            const float4 g11 = vb[(long)(cy1 * Wl + cx1) * (NH * 8)];

            const float awv = a[lvl * 4 + p] * inv;
            acc.x += awv * (w00 * g00.x + w10 * g10.x + w01 * g01.x + w11 * g11.x);
            acc.y += awv * (w00 * g00.y + w10 * g10.y + w01 * g01.y + w11 * g11.y);
            acc.z += awv * (w00 * g00.z + w10 * g10.z + w01 * g01.z + w11 * g11.z);
            acc.w += awv * (w00 * g00.w + w10 * g10.w + w01 * g01.w + w11 * g11.w);
        }
    }
    bf16x4 ob;
    ob[0] = f2bf(acc.x); ob[1] = f2bf(acc.y);
    ob[2] = f2bf(acc.z); ob[3] = f2bf(acc.w);
    ATTb[row * 64 + h * 8 + d4] = ob;
}

// ---------------------------------------------------------------------------
// LN(X+Y)*g+b with optional fp32 / bf16 / bf16(+pos) outputs.
// ---------------------------------------------------------------------------
__global__ __launch_bounds__(256) void add_ln_kernel(
    const float* __restrict__ X, const float* __restrict__ Y,
    const float* __restrict__ g, const float* __restrict__ b,
    float* __restrict__ outf, short* __restrict__ outb,
    short* __restrict__ outq, const float* __restrict__ pos)
{
    const long row = blockIdx.x;
    const int  t   = threadIdx.x;
    const int lane = t & 63, wid = t >> 6;
    __shared__ float red[4];

    float v = X[row * DM + t] + Y[row * DM + t];

    float s = v;
    #pragma unroll
    for (int o = 32; o > 0; o >>= 1) s += __shfl_down(s, o, 64);
    if (lane == 0) red[wid] = s;
    __syncthreads();
    const float mean = (red[0] + red[1] + red[2] + red[3]) * (1.f / DM);
    __syncthreads();

    const float dv = v - mean;
    float s2 = dv * dv;
    #pragma unroll
    for (int o = 32; o > 0; o >>= 1) s2 += __shfl_down(s2, o, 64);
    if (lane == 0) red[wid] = s2;
    __syncthreads();
    const float var = (red[0] + red[1] + red[2] + red[3]) * (1.f / DM);

    const float r = dv * rsqrtf(var + 1e-5f) * g[t] + b[t];
    if (outf) outf[row * DM + t] = r;
    if (outb) outb[row * DM + t] = f2bf(r);
    if (outq) outq[row * DM + t] = f2bf(r + pos[row * DM + t]);
}

// ---------------------------------------------------------------------------
extern "C" void kernel_launch(void* const* d_in, const int* in_sizes, int n_in,
                              void* d_out, int out_size, void* d_ws, size_t ws_size,
                              hipStream_t stream)
{
    const float* src = (const float*)d_in[0];
    const float* pos = (const float*)d_in[1];
    const float* vr  = (const float*)d_in[2];
    const float* Wv_   = (const float*)d_in[3];
    const float* bv_   = (const float*)d_in[4];
    const float* Woff_ = (const float*)d_in[5];
    const float* boff_ = (const float*)d_in[6];
    const float* Wa_   = (const float*)d_in[7];
    const float* ba_   = (const float*)d_in[8];
    const float* Wo_   = (const float*)d_in[9];
    const float* bo_   = (const float*)d_in[10];
    const float* g1_   = (const float*)d_in[11];
    const float* be1_  = (const float*)d_in[12];
    const float* Wl1_  = (const float*)d_in[13];
    const float* bl1_  = (const float*)d_in[14];
    const float* Wl2_  = (const float*)d_in[15];
    const float* bl2_  = (const float*)d_in[16];
    const float* g2_   = (const float*)d_in[17];
    const float* be2_  = (const float*)d_in[18];

    const long SZ = (long)MROWS * DM;        // 2,785,280 elements
    float* ws = (float*)d_ws;
    float* V    = ws;                         // f32 M x 256
    float* OFF  = V   + SZ;                   // f32 M x 256
    float* AW   = OFF + SZ;                   // f32 M x 128
    float* AO   = AW  + (long)MROWS * 128;    // f32 M x 256 (Wo out, FFN2 out)
    float* XA   = AO  + SZ;                   // f32 M x 256 (LN1 out)
    float* XB   = XA  + SZ;                   // f32 M x 256 (LN2 out, layer0)
    short* curb = (short*)(XB + SZ);          // bf16 M x 256
    short* qb   = curb + SZ;                  // bf16 M x 256
    short* ATTb = qb   + SZ;                  // bf16 M x 256
    short* XAb  = ATTb + SZ;                  // bf16 M x 256
    short* FFNb = XAb  + SZ;                  // bf16 M x 1024
    short* Wt   = FFNb + (long)MROWS * DFFN;  // 2 x 753664 bf16 weights

    const dim3 blk(256);
    const int GYM = MROWS / 128;              // 85

    hipLaunchKernelGGL(transpose_convert_all, dim3(1472), blk, 0, stream,
                       Wv_, Woff_, Wa_, Wo_, Wl1_, Wl2_, Wt);
    hipLaunchKernelGGL(convert_src, dim3(SZ / 4 / 256), blk, 0, stream,
                       (const float4*)src, (const float4*)pos,
                       (bf16x4*)curb, (bf16x4*)qb);

    const float* cur = src;
    for (int l = 0; l < 2; ++l) {
        const short* Wbase = Wt + (long)l * 753664;
        const float* bv   = bv_   + (long)l * DM;
        const float* boff = boff_ + (long)l * 256;
        const float* ba   = ba_   + (long)l * 128;
        const float* bo   = bo_   + (long)l * DM;
        const float* g1   = g1_   + (long)l * DM;
        const float* be1  = be1_  + (long)l * DM;
        const float* bl1  = bl1_  + (long)l * DFFN;
        const float* bl2  = bl2_  + (long)l * DM;
        const float* g2   = g2_   + (long)l * DM;
        const float* be2  = be2_  + (long)l * DM;

        // [V | OFF | AW] = [curb | qb] @ [Wv|Woff|Wa]   (BN=128, 5x85 blocks)
        hipLaunchKernelGGL(gemm_qkv128, dim3(5, GYM), blk, 0, stream,
                           curb, qb, Wbase, bv, boff, ba, V, OFF, AW);
        hipLaunchKernelGGL(deform_attn_v2, dim3(MROWS / 4), blk, 0, stream,
                           (const float4*)V, OFF, AW, vr, (bf16x4*)ATTb);
        // AO = ATT @ Wo + bo   (BN=64, 4x85)
        hipLaunchKernelGGL((gemm128<64, 0, 0>), dim3(4, GYM), blk, 0, stream,
                           ATTb, Wbase + 163840, bo, AO, (short*)nullptr, 256, 256);
        // XA = LN(cur + AO); bf16 copy for FFN1
        hipLaunchKernelGGL(add_ln_kernel, dim3(MROWS), blk, 0, stream,
                           cur, AO, g1, be1, XA, XAb, (short*)nullptr,
                           (const float*)nullptr);
        // FFNb = relu(XA @ Wl1 + bl1)  bf16 out  (BN=128, 8x85)
        hipLaunchKernelGGL((gemm128<128, 1, 1>), dim3(8, GYM), blk, 0, stream,
                           XAb, Wbase + 229376, bl1, (float*)nullptr, FFNb, 1024, 256);
        // AO = FFNb @ Wl2 + bl2   (BN=64, 4x85, K=1024)
        hipLaunchKernelGGL((gemm128<64, 0, 0>), dim3(4, GYM), blk, 0, stream,
                           FFNb, Wbase + 491520, bl2, AO, (short*)nullptr, 256, 1024);
        // out = LN(XA + AO); layer0 also emits bf16 cur and bf16(cur+pos)
        if (l == 0) {
            hipLaunchKernelGGL(add_ln_kernel, dim3(MROWS), blk, 0, stream,
                               XA, AO, g2, be2, XB, curb, qb, pos);
            cur = XB;
        } else {
            hipLaunchKernelGGL(add_ln_kernel, dim3(MROWS), blk, 0, stream,
                               XA, AO, g2, be2, (float*)d_out, (short*)nullptr,
                               (short*)nullptr, (const float*)nullptr);
        }
    }
}

// Round 6
// 325.387 us; speedup vs baseline: 2.9062x; 1.1493x over previous
//
#include <hip/hip_runtime.h>
#include <math.h>

#define LEN   5440
#define NB    2
#define MROWS (NB * LEN)   // 10880
#define DM    256
#define NH    8
#define HD    32
#define NLV   4
#define NPT   4
#define DFFN  1024

typedef __attribute__((ext_vector_type(8))) short bf16x8;
typedef __attribute__((ext_vector_type(4))) short bf16x4;
typedef __attribute__((ext_vector_type(4))) float f32x4;

__device__ __forceinline__ short f2bf(float f) {
    union { float f; unsigned u; } cv; cv.f = f;
    unsigned r = cv.u + 0x7fffu + ((cv.u >> 16) & 1u);   // RNE
    return (short)(r >> 16);
}
__device__ __forceinline__ float bf2f(short s) {
    union { unsigned u; float f; } cv;
    cv.u = ((unsigned)(unsigned short)s) << 16;
    return cv.f;
}

// ---------------------------------------------------------------------------
// One-shot: transpose+convert all 12 weight matrices fp32 [K][N] -> bf16 [N][K].
// Per-layer short offsets: Wv@0 | Woff@65536 | Wa@131072 (contiguous 640 rows,
// K=256, fused qkv), Wo@163840, Wl1@229376, Wl2@491520; layer stride 753664.
// ---------------------------------------------------------------------------
__global__ __launch_bounds__(256) void transpose_convert_all(
    const float* __restrict__ Wv,  const float* __restrict__ Woff,
    const float* __restrict__ Wa,  const float* __restrict__ Wo,
    const float* __restrict__ Wl1, const float* __restrict__ Wl2,
    short* __restrict__ out)
{
    int bx = blockIdx.x;
    int l  = bx / 736;
    int t  = bx % 736;
    const float* src; int K, N; long doff;
    if      (t < 64)  { src = Wv;   K = 256;  N = 256;  doff = 0;      }
    else if (t < 128) { src = Woff; K = 256;  N = 256;  doff = 65536;  t -= 64;  }
    else if (t < 160) { src = Wa;   K = 256;  N = 128;  doff = 131072; t -= 128; }
    else if (t < 224) { src = Wo;   K = 256;  N = 256;  doff = 163840; t -= 160; }
    else if (t < 480) { src = Wl1;  K = 256;  N = 1024; doff = 229376; t -= 224; }
    else              { src = Wl2;  K = 1024; N = 256;  doff = 491520; t -= 480; }
    src += (long)l * K * N;
    short* dst = out + (long)l * 753664 + doff;

    const int ntx = N / 32;
    const int n0 = (t % ntx) * 32, k0 = (t / ntx) * 32;

    __shared__ short T[32][33];
    const int tid = threadIdx.x;
    {
        const int n = tid & 31, kq = tid >> 5;
        #pragma unroll
        for (int i = 0; i < 4; ++i) {
            int k = kq * 4 + i;
            T[n][k] = f2bf(src[(long)(k0 + k) * N + n0 + n]);
        }
    }
    __syncthreads();
    {
        const int k = tid & 31, nq = tid >> 5;
        #pragma unroll
        for (int i = 0; i < 4; ++i) {
            int n = nq * 4 + i;
            dst[(long)(n0 + n) * K + k0 + k] = T[n][k];
        }
    }
}

// ---------------------------------------------------------------------------
// src -> bf16(src), bf16(src+pos)
// ---------------------------------------------------------------------------
__global__ __launch_bounds__(256) void convert_src(
    const float4* __restrict__ s4, const float4* __restrict__ p4,
    bf16x4* __restrict__ curb, bf16x4* __restrict__ qb)
{
    const int i = blockIdx.x * 256 + threadIdx.x;
    float4 s = s4[i], p = p4[i];
    bf16x4 c, q;
    c[0] = f2bf(s.x); c[1] = f2bf(s.y); c[2] = f2bf(s.z); c[3] = f2bf(s.w);
    q[0] = f2bf(s.x + p.x); q[1] = f2bf(s.y + p.y);
    q[2] = f2bf(s.z + p.z); q[3] = f2bf(s.w + p.w);
    curb[i] = c; qb[i] = q;
}

// ---------------------------------------------------------------------------
// MFMA bf16 GEMM, 128 x BN tile, BK=32. Explicit global->reg prefetch +
// ds_write_b128 into PADDED LDS rows (stride 40 shorts = 80 B; addr16 =
// 5*row + chunk -> the measured-conflict-free class, R2/R4: 0 conflicts).
// 4 waves: wave w rows (w&1)*64, cols (w>>1)*(BN/2); 4 x NF 16x16 subtiles.
// Epilogue modes: 0 = f32 row-major, 1 = bf16 row-major (+optional relu),
// 2 = bf16 into V-layout (n,h,len,d) planes.
// ---------------------------------------------------------------------------
template <int BN, int RELU, int OMODE>
__device__ __forceinline__ void gemm_core128(
    short* As, short* Bs,
    const short* __restrict__ A, const short* __restrict__ Wt,
    const float* __restrict__ bias, float* __restrict__ Cf,
    short* __restrict__ Cb,
    int ldc, int m0, int wrow0, int ccol0, int K)
{
    constexpr int NF = BN / 32;            // B subtiles per wave
    constexpr int NBJ = BN / 64;           // B staging chunks per thread
    const int t    = threadIdx.x;
    const int wave = t >> 6, lane = t & 63;
    const int wm   = (wave & 1) * 64;
    const int wn   = (wave >> 1) * (BN / 2);
    const int lm   = lane & 15;
    const int chkg = lane >> 4;            // frag k-chunk 0..3
    const int srow = t >> 2;               // staging row 0..63 (+64j)
    const int sc   = t & 3;                // staging chunk 0..3

    f32x4 acc[4][NF] = {};
    bf16x8 ar[2], br[NBJ];

    // prefetch k0 = 0
    #pragma unroll
    for (int j = 0; j < 2; ++j)
        ar[j] = *(const bf16x8*)(A + (long)(m0 + srow + 64 * j) * K + sc * 8);
    #pragma unroll
    for (int j = 0; j < NBJ; ++j)
        br[j] = *(const bf16x8*)(Wt + (long)(wrow0 + srow + 64 * j) * K + sc * 8);

    for (int k0 = 0; k0 < K; k0 += 32) {
        __syncthreads();   // previous iter's frag reads complete
        #pragma unroll
        for (int j = 0; j < 2; ++j)
            *(bf16x8*)(&As[(srow + 64 * j) * 40 + sc * 8]) = ar[j];
        #pragma unroll
        for (int j = 0; j < NBJ; ++j)
            *(bf16x8*)(&Bs[(srow + 64 * j) * 40 + sc * 8]) = br[j];
        __syncthreads();

        if (k0 + 32 < K) {   // prefetch next, overlapping MFMA phase
            #pragma unroll
            for (int j = 0; j < 2; ++j)
                ar[j] = *(const bf16x8*)(A + (long)(m0 + srow + 64 * j) * K + k0 + 32 + sc * 8);
            #pragma unroll
            for (int j = 0; j < NBJ; ++j)
                br[j] = *(const bf16x8*)(Wt + (long)(wrow0 + srow + 64 * j) * K + k0 + 32 + sc * 8);
        }

        bf16x8 af[4], bfv[NF];
        #pragma unroll
        for (int s = 0; s < 4; ++s)
            af[s] = *(const bf16x8*)(&As[(wm + s * 16 + lm) * 40 + chkg * 8]);
        #pragma unroll
        for (int u = 0; u < NF; ++u)
            bfv[u] = *(const bf16x8*)(&Bs[(wn + u * 16 + lm) * 40 + chkg * 8]);
        #pragma unroll
        for (int s = 0; s < 4; ++s)
            #pragma unroll
            for (int u = 0; u < NF; ++u)
                acc[s][u] = __builtin_amdgcn_mfma_f32_16x16x32_bf16(
                    af[s], bfv[u], acc[s][u], 0, 0, 0);
    }

    // ---- epilogue: D col=lane&15, row=(lane>>4)*4+r ----
    const int col = lane & 15;
    const int rq  = (lane >> 4) * 4;
    #pragma unroll
    for (int s = 0; s < 4; ++s) {
        #pragma unroll
        for (int u = 0; u < NF; ++u) {
            const int gn = ccol0 + wn + u * 16 + col;
            const float bb = bias[gn];
            #pragma unroll
            for (int r = 0; r < 4; ++r) {
                const int gm = m0 + wm + s * 16 + rq + r;
                float v = acc[s][u][r] + bb;
                if (RELU) v = fmaxf(v, 0.f);
                if (OMODE == 0) {
                    Cf[(long)gm * ldc + gn] = v;
                } else if (OMODE == 1) {
                    Cb[(long)gm * ldc + gn] = f2bf(v);
                } else {
                    // V layout: (n*8+h) plane, pixel, d   (bf16)
                    const int n   = gm / LEN;
                    const int pix = gm - n * LEN;
                    const int h   = gn >> 5, d = gn & 31;
                    Cb[((long)(n * NH + h) * LEN + pix) * 32 + d] = f2bf(v);
                }
            }
        }
    }
}

template <int BN, int RELU, int OMODE>
__global__ __launch_bounds__(256) void gemm128(
    const short* __restrict__ A, const short* __restrict__ Wt,
    const float* __restrict__ bias, float* Cf, short* Cb, int ldc, int K)
{
    __shared__ __align__(16) short As[128 * 40];
    __shared__ __align__(16) short Bs[BN * 40];
    gemm_core128<BN, RELU, OMODE>(As, Bs, A, Wt, bias, Cf, Cb, ldc,
                                  blockIdx.y * 128, blockIdx.x * BN,
                                  blockIdx.x * BN, K);
}

// Fused query-side GEMM: [Vb | OFF | AW] over N=640 (Wv|Woff|Wa rows contiguous).
__global__ __launch_bounds__(256) void gemm_qkv128(
    const short* __restrict__ curb, const short* __restrict__ qb,
    const short* __restrict__ Wt, const float* __restrict__ bv,
    const float* __restrict__ boff, const float* __restrict__ ba,
    short* __restrict__ Vb, float* __restrict__ OFF, float* __restrict__ AW)
{
    __shared__ __align__(16) short As[128 * 40];
    __shared__ __align__(16) short Bs[128 * 40];
    const int n0 = blockIdx.x * 128;   // 0,128,256,384,512
    if (n0 < 256) {
        gemm_core128<128, 0, 2>(As, Bs, curb, Wt, bv, (float*)nullptr, Vb,
                                256, blockIdx.y * 128, n0, n0, 256);
    } else if (n0 < 512) {
        gemm_core128<128, 0, 0>(As, Bs, qb, Wt, boff, OFF, (short*)nullptr,
                                256, blockIdx.y * 128, n0, n0 - 256, 256);
    } else {
        gemm_core128<128, 0, 0>(As, Bs, qb, Wt, ba, AW, (short*)nullptr,
                                128, blockIdx.y * 128, n0, n0 - 512, 256);
    }
}

// ---------------------------------------------------------------------------
// Deformable attention sampling v3. One wave/query; lane = h*8+d4.
// V is bf16 in (n*8+h, len, 32) planes -> bf16x4 (8 B) gathers with strong
// spatial locality (x-neighbor corners 64 B apart within a plane).
// ---------------------------------------------------------------------------
__global__ __launch_bounds__(256) void deform_attn_v3(
    const short* __restrict__ Vb,    // (NB*NH, LEN, 32) bf16
    const float* __restrict__ OFF,   // (MROWS, 256)
    const float* __restrict__ AW,    // (MROWS, 128)
    const float* __restrict__ vr,    // (NB, NLV, 2)
    bf16x4* __restrict__ ATTb)       // (MROWS, 64) bf16x4
{
    const int starts[5] = {0, 4096, 5120, 5376, 5440};
    const int dims[4]   = {64, 32, 16, 8};

    const int wave = threadIdx.x >> 6;
    const int lane = threadIdx.x & 63;
    const int h    = lane >> 3;
    const int d4   = lane & 7;

    const int gq = blockIdx.x * 4 + wave;
    const int n  = gq / LEN;
    const int q  = gq % LEN;

    int lq = 3;
    if (q < 4096) lq = 0; else if (q < 5120) lq = 1; else if (q < 5376) lq = 2;
    const int r  = q - starts[lq];
    const int Wq = dims[lq];
    const int gy = r / Wq, gx = r % Wq;
    const float vrxq = vr[(n * NLV + lq) * 2 + 0];
    const float vryq = vr[(n * NLV + lq) * 2 + 1];
    const float rx = (gx + 0.5f) / (vrxq * Wq);
    const float ry = (gy + 0.5f) / (vryq * Wq);

    const long row = (long)n * LEN + q;

    const float* awp = AW + row * 128 + h * 16;
    float a[16];
    float mx = -1e30f;
    #pragma unroll
    for (int i = 0; i < 16; ++i) { a[i] = awp[i]; mx = fmaxf(mx, a[i]); }
    float s = 0.f;
    #pragma unroll
    for (int i = 0; i < 16; ++i) { a[i] = __expf(a[i] - mx); s += a[i]; }
    const float inv = 1.f / s;

    const float* offp = OFF + row * 256 + h * 32;

    float4 acc = {0.f, 0.f, 0.f, 0.f};
    #pragma unroll
    for (int lvl = 0; lvl < NLV; ++lvl) {
        const int Hl = dims[lvl];
        const int Wl = Hl;
        const float fW = (float)Wl;
        const int sb = starts[lvl];
        const float lx = rx * vr[(n * NLV + lvl) * 2 + 0];
        const float ly = ry * vr[(n * NLV + lvl) * 2 + 1];
        const short* vb = Vb + ((long)(n * NH + h) * LEN + sb) * 32 + d4 * 4;
        #pragma unroll
        for (int p = 0; p < NPT; ++p) {
            const float ox = offp[lvl * 8 + p * 2 + 0];
            const float oy = offp[lvl * 8 + p * 2 + 1];
            const float x = fmaf(lx, fW, ox) - 0.5f;
            const float y = fmaf(ly, fW, oy) - 0.5f;
            const float x0f = floorf(x), y0f = floorf(y);
            const int ix0 = (int)x0f, iy0 = (int)y0f;
            const float wx1 = x - x0f, wy1 = y - y0f;
            const float wx0 = 1.f - wx1, wy0 = 1.f - wy1;

            const bool vx0 = (ix0 >= 0)     && (ix0 < Wl);
            const bool vx1 = (ix0 + 1 >= 0) && (ix0 + 1 < Wl);
            const bool vy0 = (iy0 >= 0)     && (iy0 < Hl);
            const bool vy1 = (iy0 + 1 >= 0) && (iy0 + 1 < Hl);
            const int cx0 = min(max(ix0, 0), Wl - 1);
            const int cx1 = min(max(ix0 + 1, 0), Wl - 1);
            const int cy0 = min(max(iy0, 0), Hl - 1);
            const int cy1 = min(max(iy0 + 1, 0), Hl - 1);

            const float w00 = (vx0 && vy0) ? wx0 * wy0 : 0.f;
            const float w10 = (vx1 && vy0) ? wx1 * wy0 : 0.f;
            const float w01 = (vx0 && vy1) ? wx0 * wy1 : 0.f;
            const float w11 = (vx1 && vy1) ? wx1 * wy1 : 0.f;

            const bf16x4 g00 = *(const bf16x4*)(vb + (long)(cy0 * Wl + cx0) * 32);
            const bf16x4 g10 = *(const bf16x4*)(vb + (long)(cy0 * Wl + cx1) * 32);
            const bf16x4 g01 = *(const bf16x4*)(vb + (long)(cy1 * Wl + cx0) * 32);
            const bf16x4 g11 = *(const bf16x4*)(vb + (long)(cy1 * Wl + cx1) * 32);

            const float awv = a[lvl * 4 + p] * inv;
            #pragma unroll
            for (int e = 0; e < 4; ++e) {
                float sv = w00 * bf2f(g00[e]) + w10 * bf2f(g10[e])
                         + w01 * bf2f(g01[e]) + w11 * bf2f(g11[e]);
                (&acc.x)[e] += awv * sv;
            }
        }
    }
    bf16x4 ob;
    ob[0] = f2bf(acc.x); ob[1] = f2bf(acc.y);
    ob[2] = f2bf(acc.z); ob[3] = f2bf(acc.w);
    ATTb[row * 64 + h * 8 + d4] = ob;
}

// ---------------------------------------------------------------------------
// LN(X+Y)*g+b with optional fp32 / bf16 / bf16(+pos) outputs.
// ---------------------------------------------------------------------------
__global__ __launch_bounds__(256) void add_ln_kernel(
    const float* __restrict__ X, const float* __restrict__ Y,
    const float* __restrict__ g, const float* __restrict__ b,
    float* __restrict__ outf, short* __restrict__ outb,
    short* __restrict__ outq, const float* __restrict__ pos)
{
    const long row = blockIdx.x;
    const int  t   = threadIdx.x;
    const int lane = t & 63, wid = t >> 6;
    __shared__ float red[4];

    float v = X[row * DM + t] + Y[row * DM + t];

    float s = v;
    #pragma unroll
    for (int o = 32; o > 0; o >>= 1) s += __shfl_down(s, o, 64);
    if (lane == 0) red[wid] = s;
    __syncthreads();
    const float mean = (red[0] + red[1] + red[2] + red[3]) * (1.f / DM);
    __syncthreads();

    const float dv = v - mean;
    float s2 = dv * dv;
    #pragma unroll
    for (int o = 32; o > 0; o >>= 1) s2 += __shfl_down(s2, o, 64);
    if (lane == 0) red[wid] = s2;
    __syncthreads();
    const float var = (red[0] + red[1] + red[2] + red[3]) * (1.f / DM);

    const float r = dv * rsqrtf(var + 1e-5f) * g[t] + b[t];
    if (outf) outf[row * DM + t] = r;
    if (outb) outb[row * DM + t] = f2bf(r);
    if (outq) outq[row * DM + t] = f2bf(r + pos[row * DM + t]);
}

// ---------------------------------------------------------------------------
extern "C" void kernel_launch(void* const* d_in, const int* in_sizes, int n_in,
                              void* d_out, int out_size, void* d_ws, size_t ws_size,
                              hipStream_t stream)
{
    const float* src = (const float*)d_in[0];
    const float* pos = (const float*)d_in[1];
    const float* vr  = (const float*)d_in[2];
    const float* Wv_   = (const float*)d_in[3];
    const float* bv_   = (const float*)d_in[4];
    const float* Woff_ = (const float*)d_in[5];
    const float* boff_ = (const float*)d_in[6];
    const float* Wa_   = (const float*)d_in[7];
    const float* ba_   = (const float*)d_in[8];
    const float* Wo_   = (const float*)d_in[9];
    const float* bo_   = (const float*)d_in[10];
    const float* g1_   = (const float*)d_in[11];
    const float* be1_  = (const float*)d_in[12];
    const float* Wl1_  = (const float*)d_in[13];
    const float* bl1_  = (const float*)d_in[14];
    const float* Wl2_  = (const float*)d_in[15];
    const float* bl2_  = (const float*)d_in[16];
    const float* g2_   = (const float*)d_in[17];
    const float* be2_  = (const float*)d_in[18];

    const long SZ = (long)MROWS * DM;        // 2,785,280 elements
    float* ws = (float*)d_ws;
    float* OFF  = ws;                         // f32 M x 256
    float* AW   = OFF + SZ;                   // f32 M x 128
    float* AO   = AW  + (long)MROWS * 128;    // f32 M x 256
    float* XA   = AO  + SZ;                   // f32 M x 256 (LN1 out)
    float* XB   = XA  + SZ;                   // f32 M x 256 (LN2 out, layer0)
    short* Vb   = (short*)(XB + SZ);          // bf16 (NB*NH, LEN, 32)
    short* curb = Vb   + SZ;                  // bf16 M x 256
    short* qb   = curb + SZ;                  // bf16 M x 256
    short* ATTb = qb   + SZ;                  // bf16 M x 256
    short* XAb  = ATTb + SZ;                  // bf16 M x 256
    short* FFNb = XAb  + SZ;                  // bf16 M x 1024
    short* Wt   = FFNb + (long)MROWS * DFFN;  // 2 x 753664 bf16 weights

    const dim3 blk(256);
    const int GYM = MROWS / 128;              // 85

    hipLaunchKernelGGL(transpose_convert_all, dim3(1472), blk, 0, stream,
                       Wv_, Woff_, Wa_, Wo_, Wl1_, Wl2_, Wt);
    hipLaunchKernelGGL(convert_src, dim3(SZ / 4 / 256), blk, 0, stream,
                       (const float4*)src, (const float4*)pos,
                       (bf16x4*)curb, (bf16x4*)qb);

    const float* cur = src;
    for (int l = 0; l < 2; ++l) {
        const short* Wbase = Wt + (long)l * 753664;
        const float* bv   = bv_   + (long)l * DM;
        const float* boff = boff_ + (long)l * 256;
        const float* ba   = ba_   + (long)l * 128;
        const float* bo   = bo_   + (long)l * DM;
        const float* g1   = g1_   + (long)l * DM;
        const float* be1  = be1_  + (long)l * DM;
        const float* bl1  = bl1_  + (long)l * DFFN;
        const float* bl2  = bl2_  + (long)l * DM;
        const float* g2   = g2_   + (long)l * DM;
        const float* be2  = be2_  + (long)l * DM;

        // [Vb | OFF | AW] = [curb | qb] @ [Wv|Woff|Wa]   (BN=128, 5x85)
        hipLaunchKernelGGL(gemm_qkv128, dim3(5, GYM), blk, 0, stream,
                           curb, qb, Wbase, bv, boff, ba, Vb, OFF, AW);
        hipLaunchKernelGGL(deform_attn_v3, dim3(MROWS / 4), blk, 0, stream,
                           Vb, OFF, AW, vr, (bf16x4*)ATTb);
        // AO = ATT @ Wo + bo   (BN=64, 4x85)
        hipLaunchKernelGGL((gemm128<64, 0, 0>), dim3(4, GYM), blk, 0, stream,
                           ATTb, Wbase + 163840, bo, AO, (short*)nullptr, 256, 256);
        // XA = LN(cur + AO); bf16 copy for FFN1
        hipLaunchKernelGGL(add_ln_kernel, dim3(MROWS), blk, 0, stream,
                           cur, AO, g1, be1, XA, XAb, (short*)nullptr,
                           (const float*)nullptr);
        // FFNb = relu(XA @ Wl1 + bl1)  bf16 out  (BN=128, 8x85)
        hipLaunchKernelGGL((gemm128<128, 1, 1>), dim3(8, GYM), blk, 0, stream,
                           XAb, Wbase + 229376, bl1, (float*)nullptr, FFNb, 1024, 256);
        // AO = FFNb @ Wl2 + bl2   (BN=64, 4x85, K=1024)
        hipLaunchKernelGGL((gemm128<64, 0, 0>), dim3(4, GYM), blk, 0, stream,
                           FFNb, Wbase + 491520, bl2, AO, (short*)nullptr, 256, 1024);
        // out = LN(XA + AO); layer0 also emits bf16 cur and bf16(cur+pos)
        if (l == 0) {
            hipLaunchKernelGGL(add_ln_kernel, dim3(MROWS), blk, 0, stream,
                               XA, AO, g2, be2, XB, curb, qb, pos);
            cur = XB;
        } else {
            hipLaunchKernelGGL(add_ln_kernel, dim3(MROWS), blk, 0, stream,
                               XA, AO, g2, be2, (float*)d_out, (short*)nullptr,
                               (short*)nullptr, (const float*)nullptr);
        }
    }
}

// Round 7
// 315.355 us; speedup vs baseline: 2.9987x; 1.0318x over previous
//
#include <hip/hip_runtime.h>
#include <math.h>

#define LEN   5440
#define NB    2
#define MROWS (NB * LEN)   // 10880
#define DM    256
#define NH    8
#define HD    32
#define NLV   4
#define NPT   4
#define DFFN  1024

typedef __attribute__((ext_vector_type(8))) short bf16x8;
typedef __attribute__((ext_vector_type(4))) short bf16x4;
typedef __attribute__((ext_vector_type(4))) float f32x4;

__device__ __forceinline__ short f2bf(float f) {
    union { float f; unsigned u; } cv; cv.f = f;
    unsigned r = cv.u + 0x7fffu + ((cv.u >> 16) & 1u);   // RNE
    return (short)(r >> 16);
}
__device__ __forceinline__ float bf2f(short s) {
    union { unsigned u; float f; } cv;
    cv.u = ((unsigned)(unsigned short)s) << 16;
    return cv.f;
}

// ---------------------------------------------------------------------------
// One-shot: transpose+convert all 12 weight matrices fp32 [K][N] -> bf16 [N][K].
// Per-layer short offsets: Wv@0 | Woff@65536 | Wa@131072 (contiguous 640 rows,
// K=256, fused qkv), Wo@163840, Wl1@229376, Wl2@491520; layer stride 753664.
// ---------------------------------------------------------------------------
__global__ __launch_bounds__(256) void transpose_convert_all(
    const float* __restrict__ Wv,  const float* __restrict__ Woff,
    const float* __restrict__ Wa,  const float* __restrict__ Wo,
    const float* __restrict__ Wl1, const float* __restrict__ Wl2,
    short* __restrict__ out)
{
    int bx = blockIdx.x;
    int l  = bx / 736;
    int t  = bx % 736;
    const float* src; int K, N; long doff;
    if      (t < 64)  { src = Wv;   K = 256;  N = 256;  doff = 0;      }
    else if (t < 128) { src = Woff; K = 256;  N = 256;  doff = 65536;  t -= 64;  }
    else if (t < 160) { src = Wa;   K = 256;  N = 128;  doff = 131072; t -= 128; }
    else if (t < 224) { src = Wo;   K = 256;  N = 256;  doff = 163840; t -= 160; }
    else if (t < 480) { src = Wl1;  K = 256;  N = 1024; doff = 229376; t -= 224; }
    else              { src = Wl2;  K = 1024; N = 256;  doff = 491520; t -= 480; }
    src += (long)l * K * N;
    short* dst = out + (long)l * 753664 + doff;

    const int ntx = N / 32;
    const int n0 = (t % ntx) * 32, k0 = (t / ntx) * 32;

    __shared__ short T[32][33];
    const int tid = threadIdx.x;
    {
        const int n = tid & 31, kq = tid >> 5;
        #pragma unroll
        for (int i = 0; i < 4; ++i) {
            int k = kq * 4 + i;
            T[n][k] = f2bf(src[(long)(k0 + k) * N + n0 + n]);
        }
    }
    __syncthreads();
    {
        const int k = tid & 31, nq = tid >> 5;
        #pragma unroll
        for (int i = 0; i < 4; ++i) {
            int n = nq * 4 + i;
            dst[(long)(n0 + n) * K + k0 + k] = T[n][k];
        }
    }
}

// ---------------------------------------------------------------------------
// src -> bf16(src), bf16(src+pos)
// ---------------------------------------------------------------------------
__global__ __launch_bounds__(256) void convert_src(
    const float4* __restrict__ s4, const float4* __restrict__ p4,
    bf16x4* __restrict__ curb, bf16x4* __restrict__ qb)
{
    const int i = blockIdx.x * 256 + threadIdx.x;
    float4 s = s4[i], p = p4[i];
    bf16x4 c, q;
    c[0] = f2bf(s.x); c[1] = f2bf(s.y); c[2] = f2bf(s.z); c[3] = f2bf(s.w);
    q[0] = f2bf(s.x + p.x); q[1] = f2bf(s.y + p.y);
    q[2] = f2bf(s.z + p.z); q[3] = f2bf(s.w + p.w);
    curb[i] = c; qb[i] = q;
}

// ---------------------------------------------------------------------------
// MFMA bf16 GEMM, 128 x BN tile, BK=32, padded LDS (stride 40 shorts),
// explicit global->reg prefetch. OMODE: 0 f32 row-major, 1 bf16 row-major,
// 2 bf16 into V planes (n*8+h, len, 32).
// ---------------------------------------------------------------------------
template <int BN, int RELU, int OMODE>
__device__ __forceinline__ void gemm_core128(
    short* As, short* Bs,
    const short* __restrict__ A, const short* __restrict__ Wt,
    const float* __restrict__ bias, float* __restrict__ Cf,
    short* __restrict__ Cb,
    int ldc, int m0, int wrow0, int ccol0, int K)
{
    constexpr int NF = BN / 32;
    constexpr int NBJ = BN / 64;
    const int t    = threadIdx.x;
    const int wave = t >> 6, lane = t & 63;
    const int wm   = (wave & 1) * 64;
    const int wn   = (wave >> 1) * (BN / 2);
    const int lm   = lane & 15;
    const int chkg = lane >> 4;
    const int srow = t >> 2;
    const int sc   = t & 3;

    f32x4 acc[4][NF] = {};
    bf16x8 ar[2], br[NBJ];

    #pragma unroll
    for (int j = 0; j < 2; ++j)
        ar[j] = *(const bf16x8*)(A + (long)(m0 + srow + 64 * j) * K + sc * 8);
    #pragma unroll
    for (int j = 0; j < NBJ; ++j)
        br[j] = *(const bf16x8*)(Wt + (long)(wrow0 + srow + 64 * j) * K + sc * 8);

    for (int k0 = 0; k0 < K; k0 += 32) {
        __syncthreads();
        #pragma unroll
        for (int j = 0; j < 2; ++j)
            *(bf16x8*)(&As[(srow + 64 * j) * 40 + sc * 8]) = ar[j];
        #pragma unroll
        for (int j = 0; j < NBJ; ++j)
            *(bf16x8*)(&Bs[(srow + 64 * j) * 40 + sc * 8]) = br[j];
        __syncthreads();

        if (k0 + 32 < K) {
            #pragma unroll
            for (int j = 0; j < 2; ++j)
                ar[j] = *(const bf16x8*)(A + (long)(m0 + srow + 64 * j) * K + k0 + 32 + sc * 8);
            #pragma unroll
            for (int j = 0; j < NBJ; ++j)
                br[j] = *(const bf16x8*)(Wt + (long)(wrow0 + srow + 64 * j) * K + k0 + 32 + sc * 8);
        }

        bf16x8 af[4], bfv[NF];
        #pragma unroll
        for (int s = 0; s < 4; ++s)
            af[s] = *(const bf16x8*)(&As[(wm + s * 16 + lm) * 40 + chkg * 8]);
        #pragma unroll
        for (int u = 0; u < NF; ++u)
            bfv[u] = *(const bf16x8*)(&Bs[(wn + u * 16 + lm) * 40 + chkg * 8]);
        #pragma unroll
        for (int s = 0; s < 4; ++s)
            #pragma unroll
            for (int u = 0; u < NF; ++u)
                acc[s][u] = __builtin_amdgcn_mfma_f32_16x16x32_bf16(
                    af[s], bfv[u], acc[s][u], 0, 0, 0);
    }

    const int col = lane & 15;
    const int rq  = (lane >> 4) * 4;
    #pragma unroll
    for (int s = 0; s < 4; ++s) {
        #pragma unroll
        for (int u = 0; u < NF; ++u) {
            const int gn = ccol0 + wn + u * 16 + col;
            const float bb = bias[gn];
            #pragma unroll
            for (int r = 0; r < 4; ++r) {
                const int gm = m0 + wm + s * 16 + rq + r;
                float v = acc[s][u][r] + bb;
                if (RELU) v = fmaxf(v, 0.f);
                if (OMODE == 0) {
                    Cf[(long)gm * ldc + gn] = v;
                } else if (OMODE == 1) {
                    Cb[(long)gm * ldc + gn] = f2bf(v);
                } else {
                    const int n   = gm / LEN;
                    const int pix = gm - n * LEN;
                    const int h   = gn >> 5, d = gn & 31;
                    Cb[((long)(n * NH + h) * LEN + pix) * 32 + d] = f2bf(v);
                }
            }
        }
    }
}

template <int BN, int RELU, int OMODE>
__global__ __launch_bounds__(256) void gemm128(
    const short* __restrict__ A, const short* __restrict__ Wt,
    const float* __restrict__ bias, float* Cf, short* Cb, int ldc, int K)
{
    __shared__ __align__(16) short As[128 * 40];
    __shared__ __align__(16) short Bs[BN * 40];
    gemm_core128<BN, RELU, OMODE>(As, Bs, A, Wt, bias, Cf, Cb, ldc,
                                  blockIdx.y * 128, blockIdx.x * BN,
                                  blockIdx.x * BN, K);
}

// Fused query-side GEMM: [Vb | OFF | AW] over N=640 (Wv|Woff|Wa rows contiguous).
__global__ __launch_bounds__(256) void gemm_qkv128(
    const short* __restrict__ curb, const short* __restrict__ qb,
    const short* __restrict__ Wt, const float* __restrict__ bv,
    const float* __restrict__ boff, const float* __restrict__ ba,
    short* __restrict__ Vb, float* __restrict__ OFF, float* __restrict__ AW)
{
    __shared__ __align__(16) short As[128 * 40];
    __shared__ __align__(16) short Bs[128 * 40];
    const int n0 = blockIdx.x * 128;   // 0,128,256,384,512
    if (n0 < 256) {
        gemm_core128<128, 0, 2>(As, Bs, curb, Wt, bv, (float*)nullptr, Vb,
                                256, blockIdx.y * 128, n0, n0, 256);
    } else if (n0 < 512) {
        gemm_core128<128, 0, 0>(As, Bs, qb, Wt, boff, OFF, (short*)nullptr,
                                256, blockIdx.y * 128, n0, n0 - 256, 256);
    } else {
        gemm_core128<128, 0, 0>(As, Bs, qb, Wt, ba, AW, (short*)nullptr,
                                128, blockIdx.y * 128, n0, n0 - 512, 256);
    }
}

// ---------------------------------------------------------------------------
// Fused GEMM (M-tile 32, full N=256) + residual add + LayerNorm epilogue.
// 4 waves: wave w owns rows (w&1)*16, cols (w>>1)*128 (1x8 subtiles).
// Row stats: 16-lane xor-shuffle over cols + cross-colhalf LDS combine.
// Outputs: outf f32 (always), outb bf16 (opt), outq bf16(out+pos) (opt).
// ---------------------------------------------------------------------------
__global__ __launch_bounds__(256) void gemm_ln(
    const short* __restrict__ A, const short* __restrict__ Wt,
    const float* __restrict__ bias, const float* __restrict__ resid,
    const float* __restrict__ g, const float* __restrict__ be,
    float* __restrict__ outf, short* __restrict__ outb,
    short* __restrict__ outq, const float* __restrict__ pos, int K)
{
    __shared__ __align__(16) short As[32 * 40];
    __shared__ __align__(16) short Bs[256 * 40];
    __shared__ float red[2][32][2];

    const int t    = threadIdx.x;
    const int wave = t >> 6, lane = t & 63;
    const int wm   = (wave & 1) * 16;
    const int wn   = (wave >> 1) * 128;
    const int lm   = lane & 15;
    const int chkg = lane >> 4;
    const int srow = t >> 2;          // 0..63
    const int sc   = t & 3;
    const int m0   = blockIdx.x * 32;
    const bool doA = (t < 128);       // wave-uniform (waves 0,1)

    f32x4 acc[8] = {};
    bf16x8 ar, br[4];

    if (doA) ar = *(const bf16x8*)(A + (long)(m0 + srow) * K + sc * 8);
    #pragma unroll
    for (int j = 0; j < 4; ++j)
        br[j] = *(const bf16x8*)(Wt + (long)(srow + 64 * j) * K + sc * 8);

    for (int k0 = 0; k0 < K; k0 += 32) {
        __syncthreads();
        if (doA) *(bf16x8*)(&As[srow * 40 + sc * 8]) = ar;
        #pragma unroll
        for (int j = 0; j < 4; ++j)
            *(bf16x8*)(&Bs[(srow + 64 * j) * 40 + sc * 8]) = br[j];
        __syncthreads();

        if (k0 + 32 < K) {
            if (doA) ar = *(const bf16x8*)(A + (long)(m0 + srow) * K + k0 + 32 + sc * 8);
            #pragma unroll
            for (int j = 0; j < 4; ++j)
                br[j] = *(const bf16x8*)(Wt + (long)(srow + 64 * j) * K + k0 + 32 + sc * 8);
        }

        bf16x8 af = *(const bf16x8*)(&As[(wm + lm) * 40 + chkg * 8]);
        #pragma unroll
        for (int u = 0; u < 8; ++u) {
            bf16x8 bfv = *(const bf16x8*)(&Bs[(wn + u * 16 + lm) * 40 + chkg * 8]);
            acc[u] = __builtin_amdgcn_mfma_f32_16x16x32_bf16(af, bfv, acc[u], 0, 0, 0);
        }
    }

    // ---- epilogue: v = acc + bias + residual ----
    const int rq = (lane >> 4) * 4;
    #pragma unroll
    for (int u = 0; u < 8; ++u) {
        const int gn = wn + u * 16 + lm;
        const float bb = bias[gn];
        #pragma unroll
        for (int r = 0; r < 4; ++r) {
            const int gm = m0 + wm + rq + r;
            acc[u][r] += bb + resid[(long)gm * DM + gn];
        }
    }

    // per-row partial sums over this wave's 128 cols
    float rs[4], r2[4];
    #pragma unroll
    for (int r = 0; r < 4; ++r) {
        float s = 0.f, s2 = 0.f;
        #pragma unroll
        for (int u = 0; u < 8; ++u) { const float v = acc[u][r]; s += v; s2 += v * v; }
        rs[r] = s; r2[r] = s2;
    }
    #pragma unroll
    for (int o = 1; o < 16; o <<= 1) {
        #pragma unroll
        for (int r = 0; r < 4; ++r) {
            rs[r] += __shfl_xor(rs[r], o, 64);
            r2[r] += __shfl_xor(r2[r], o, 64);
        }
    }
    if (lm == 0) {
        #pragma unroll
        for (int r = 0; r < 4; ++r) {
            red[wave >> 1][wm + rq + r][0] = rs[r];
            red[wave >> 1][wm + rq + r][1] = r2[r];
        }
    }
    __syncthreads();
    #pragma unroll
    for (int r = 0; r < 4; ++r) {
        const int row = wm + rq + r;
        const float ts = red[0][row][0] + red[1][row][0];
        const float t2 = red[0][row][1] + red[1][row][1];
        const float mean = ts * (1.f / DM);
        const float var  = t2 * (1.f / DM) - mean * mean;
        rs[r] = mean;
        r2[r] = rsqrtf(var + 1e-5f);
    }
    #pragma unroll
    for (int u = 0; u < 8; ++u) {
        const int gn = wn + u * 16 + lm;
        const float gg = g[gn], bbe = be[gn];
        #pragma unroll
        for (int r = 0; r < 4; ++r) {
            const int gm = m0 + wm + rq + r;
            const float o = (acc[u][r] - rs[r]) * r2[r] * gg + bbe;
            outf[(long)gm * DM + gn] = o;
            if (outb) outb[(long)gm * DM + gn] = f2bf(o);
            if (outq) outq[(long)gm * DM + gn] = f2bf(o + pos[(long)gm * DM + gn]);
        }
    }
}

// ---------------------------------------------------------------------------
// Deformable attention sampling v3 (unchanged from R6).
// ---------------------------------------------------------------------------
__global__ __launch_bounds__(256) void deform_attn_v3(
    const short* __restrict__ Vb,    // (NB*NH, LEN, 32) bf16
    const float* __restrict__ OFF,   // (MROWS, 256)
    const float* __restrict__ AW,    // (MROWS, 128)
    const float* __restrict__ vr,    // (NB, NLV, 2)
    bf16x4* __restrict__ ATTb)       // (MROWS, 64) bf16x4
{
    const int starts[5] = {0, 4096, 5120, 5376, 5440};
    const int dims[4]   = {64, 32, 16, 8};

    const int wave = threadIdx.x >> 6;
    const int lane = threadIdx.x & 63;
    const int h    = lane >> 3;
    const int d4   = lane & 7;

    const int gq = blockIdx.x * 4 + wave;
    const int n  = gq / LEN;
    const int q  = gq % LEN;

    int lq = 3;
    if (q < 4096) lq = 0; else if (q < 5120) lq = 1; else if (q < 5376) lq = 2;
    const int r  = q - starts[lq];
    const int Wq = dims[lq];
    const int gy = r / Wq, gx = r % Wq;
    const float vrxq = vr[(n * NLV + lq) * 2 + 0];
    const float vryq = vr[(n * NLV + lq) * 2 + 1];
    const float rx = (gx + 0.5f) / (vrxq * Wq);
    const float ry = (gy + 0.5f) / (vryq * Wq);

    const long row = (long)n * LEN + q;

    const float* awp = AW + row * 128 + h * 16;
    float a[16];
    float mx = -1e30f;
    #pragma unroll
    for (int i = 0; i < 16; ++i) { a[i] = awp[i]; mx = fmaxf(mx, a[i]); }
    float s = 0.f;
    #pragma unroll
    for (int i = 0; i < 16; ++i) { a[i] = __expf(a[i] - mx); s += a[i]; }
    const float inv = 1.f / s;

    const float* offp = OFF + row * 256 + h * 32;

    float4 acc = {0.f, 0.f, 0.f, 0.f};
    #pragma unroll
    for (int lvl = 0; lvl < NLV; ++lvl) {
        const int Hl = dims[lvl];
        const int Wl = Hl;
        const float fW = (float)Wl;
        const int sb = starts[lvl];
        const float lx = rx * vr[(n * NLV + lvl) * 2 + 0];
        const float ly = ry * vr[(n * NLV + lvl) * 2 + 1];
        const short* vb = Vb + ((long)(n * NH + h) * LEN + sb) * 32 + d4 * 4;
        #pragma unroll
        for (int p = 0; p < NPT; ++p) {
            const float ox = offp[lvl * 8 + p * 2 + 0];
            const float oy = offp[lvl * 8 + p * 2 + 1];
            const float x = fmaf(lx, fW, ox) - 0.5f;
            const float y = fmaf(ly, fW, oy) - 0.5f;
            const float x0f = floorf(x), y0f = floorf(y);
            const int ix0 = (int)x0f, iy0 = (int)y0f;
            const float wx1 = x - x0f, wy1 = y - y0f;
            const float wx0 = 1.f - wx1, wy0 = 1.f - wy1;

            const bool vx0 = (ix0 >= 0)     && (ix0 < Wl);
            const bool vx1 = (ix0 + 1 >= 0) && (ix0 + 1 < Wl);
            const bool vy0 = (iy0 >= 0)     && (iy0 < Hl);
            const bool vy1 = (iy0 + 1 >= 0) && (iy0 + 1 < Hl);
            const int cx0 = min(max(ix0, 0), Wl - 1);
            const int cx1 = min(max(ix0 + 1, 0), Wl - 1);
            const int cy0 = min(max(iy0, 0), Hl - 1);
            const int cy1 = min(max(iy0 + 1, 0), Hl - 1);

            const float w00 = (vx0 && vy0) ? wx0 * wy0 : 0.f;
            const float w10 = (vx1 && vy0) ? wx1 * wy0 : 0.f;
            const float w01 = (vx0 && vy1) ? wx0 * wy1 : 0.f;
            const float w11 = (vx1 && vy1) ? wx1 * wy1 : 0.f;

            const bf16x4 g00 = *(const bf16x4*)(vb + (long)(cy0 * Wl + cx0) * 32);
            const bf16x4 g10 = *(const bf16x4*)(vb + (long)(cy0 * Wl + cx1) * 32);
            const bf16x4 g01 = *(const bf16x4*)(vb + (long)(cy1 * Wl + cx0) * 32);
            const bf16x4 g11 = *(const bf16x4*)(vb + (long)(cy1 * Wl + cx1) * 32);

            const float awv = a[lvl * 4 + p] * inv;
            #pragma unroll
            for (int e = 0; e < 4; ++e) {
                float sv = w00 * bf2f(g00[e]) + w10 * bf2f(g10[e])
                         + w01 * bf2f(g01[e]) + w11 * bf2f(g11[e]);
                (&acc.x)[e] += awv * sv;
            }
        }
    }
    bf16x4 ob;
    ob[0] = f2bf(acc.x); ob[1] = f2bf(acc.y);
    ob[2] = f2bf(acc.z); ob[3] = f2bf(acc.w);
    ATTb[row * 64 + h * 8 + d4] = ob;
}

// ---------------------------------------------------------------------------
extern "C" void kernel_launch(void* const* d_in, const int* in_sizes, int n_in,
                              void* d_out, int out_size, void* d_ws, size_t ws_size,
                              hipStream_t stream)
{
    const float* src = (const float*)d_in[0];
    const float* pos = (const float*)d_in[1];
    const float* vr  = (const float*)d_in[2];
    const float* Wv_   = (const float*)d_in[3];
    const float* bv_   = (const float*)d_in[4];
    const float* Woff_ = (const float*)d_in[5];
    const float* boff_ = (const float*)d_in[6];
    const float* Wa_   = (const float*)d_in[7];
    const float* ba_   = (const float*)d_in[8];
    const float* Wo_   = (const float*)d_in[9];
    const float* bo_   = (const float*)d_in[10];
    const float* g1_   = (const float*)d_in[11];
    const float* be1_  = (const float*)d_in[12];
    const float* Wl1_  = (const float*)d_in[13];
    const float* bl1_  = (const float*)d_in[14];
    const float* Wl2_  = (const float*)d_in[15];
    const float* bl2_  = (const float*)d_in[16];
    const float* g2_   = (const float*)d_in[17];
    const float* be2_  = (const float*)d_in[18];

    const long SZ = (long)MROWS * DM;        // 2,785,280 elements
    float* ws = (float*)d_ws;
    float* OFF  = ws;                         // f32 M x 256
    float* AW   = OFF + SZ;                   // f32 M x 128
    float* XA   = AW  + (long)MROWS * 128;    // f32 M x 256 (LN1 out)
    float* XB   = XA  + SZ;                   // f32 M x 256 (LN2 out, layer0)
    short* Vb   = (short*)(XB + SZ);          // bf16 (NB*NH, LEN, 32)
    short* curb = Vb   + SZ;                  // bf16 M x 256
    short* qb   = curb + SZ;                  // bf16 M x 256
    short* ATTb = qb   + SZ;                  // bf16 M x 256
    short* XAb  = ATTb + SZ;                  // bf16 M x 256
    short* FFNb = XAb  + SZ;                  // bf16 M x 1024
    short* Wt   = FFNb + (long)MROWS * DFFN;  // 2 x 753664 bf16 weights

    const dim3 blk(256);
    const int GYM = MROWS / 128;              // 85
    const int GLN = MROWS / 32;               // 340

    hipLaunchKernelGGL(transpose_convert_all, dim3(1472), blk, 0, stream,
                       Wv_, Woff_, Wa_, Wo_, Wl1_, Wl2_, Wt);
    hipLaunchKernelGGL(convert_src, dim3(SZ / 4 / 256), blk, 0, stream,
                       (const float4*)src, (const float4*)pos,
                       (bf16x4*)curb, (bf16x4*)qb);

    const float* cur = src;
    for (int l = 0; l < 2; ++l) {
        const short* Wbase = Wt + (long)l * 753664;
        const float* bv   = bv_   + (long)l * DM;
        const float* boff = boff_ + (long)l * 256;
        const float* ba   = ba_   + (long)l * 128;
        const float* bo   = bo_   + (long)l * DM;
        const float* g1   = g1_   + (long)l * DM;
        const float* be1  = be1_  + (long)l * DM;
        const float* bl1  = bl1_  + (long)l * DFFN;
        const float* bl2  = bl2_  + (long)l * DM;
        const float* g2   = g2_   + (long)l * DM;
        const float* be2  = be2_  + (long)l * DM;

        // [Vb | OFF | AW] = [curb | qb] @ [Wv|Woff|Wa]   (BN=128, 5x85)
        hipLaunchKernelGGL(gemm_qkv128, dim3(5, GYM), blk, 0, stream,
                           curb, qb, Wbase, bv, boff, ba, Vb, OFF, AW);
        hipLaunchKernelGGL(deform_attn_v3, dim3(MROWS / 4), blk, 0, stream,
                           Vb, OFF, AW, vr, (bf16x4*)ATTb);
        // XA = LN(cur + ATT@Wo + bo); also bf16 XAb for FFN1
        hipLaunchKernelGGL(gemm_ln, dim3(GLN), blk, 0, stream,
                           ATTb, Wbase + 163840, bo, cur, g1, be1,
                           XA, XAb, (short*)nullptr, (const float*)nullptr, 256);
        // FFNb = relu(XAb @ Wl1 + bl1)  bf16 out  (BN=128, 8x85)
        hipLaunchKernelGGL((gemm128<128, 1, 1>), dim3(8, GYM), blk, 0, stream,
                           XAb, Wbase + 229376, bl1, (float*)nullptr, FFNb, 1024, 256);
        // out = LN(XA + FFNb@Wl2 + bl2); layer0 also emits curb, qb
        if (l == 0) {
            hipLaunchKernelGGL(gemm_ln, dim3(GLN), blk, 0, stream,
                               FFNb, Wbase + 491520, bl2, XA, g2, be2,
                               XB, curb, qb, pos, 1024);
            cur = XB;
        } else {
            hipLaunchKernelGGL(gemm_ln, dim3(GLN), blk, 0, stream,
                               FFNb, Wbase + 491520, bl2, XA, g2, be2,
                               (float*)d_out, (short*)nullptr, (short*)nullptr,
                               (const float*)nullptr, 1024);
        }
    }
}